// Round 2
// baseline (221.397 us; speedup 1.0000x reference)
//
#include <hip/hip_runtime.h>
#include <cstdint>

typedef __bf16 bf16;
typedef __bf16 bf16x8 __attribute__((ext_vector_type(8)));
typedef __bf16 bf16x4 __attribute__((ext_vector_type(4)));
typedef float  f32x4  __attribute__((ext_vector_type(4)));

#define MFMA_BF16(a, b, c) __builtin_amdgcn_mfma_f32_16x16x32_bf16(a, b, c, 0, 0, 0)

// counted vmcnt wait (T4): leave N loads in flight; "memory" clobber fences
// compiler-managed LDS reads from moving above it.
#define WAITCNT_VM(n) asm volatile("s_waitcnt vmcnt(" #n ")" ::: "memory")
#define CFENCE()      asm volatile("" ::: "memory")

// async global->LDS, 16B/lane; LDS dest affine in lane (base + lane*16).
__device__ __forceinline__ void async_load16(const void* g, void* l) {
    __builtin_amdgcn_global_load_lds(
        (__attribute__((address_space(1))) uint32_t*)(uintptr_t)g,
        (__attribute__((address_space(3))) uint32_t*)(uint32_t)(uintptr_t)l,
        16, 0, 0);
}

// ---------------- fp32 -> bf16 convert ----------------
__global__ void cvt_kernel(const float* __restrict__ src, bf16* __restrict__ dst, int n4) {
    int i = blockIdx.x * blockDim.x + threadIdx.x;
    if (i < n4) {
        float4 v = ((const float4*)src)[i];
        bf16x4 o;
        o[0] = (bf16)v.x; o[1] = (bf16)v.y; o[2] = (bf16)v.z; o[3] = (bf16)v.w;
        ((bf16x4*)dst)[i] = o;
    }
}

// ---------------- QKV GEMM: counted-vmcnt 2-deep pipeline, scatter Q/K/Vt ----------------
// 768 blocks (3/CU). Per K-step: 4 async loads/thread. Prologue stages 2 tiles (8 in
// flight); steady-state wait is vmcnt(4) -> next tile's loads stay in flight across
// both barriers (latency window = 2 iterations). vmcnt(0) only on the last iteration.
__global__ __launch_bounds__(256) void gemm_qkv_kernel(
    const bf16* __restrict__ A, const bf16* __restrict__ W,
    const float* __restrict__ bias,
    bf16* __restrict__ Qb, bf16* __restrict__ Kb, bf16* __restrict__ Vt)
{
    const int Kd = 1024;
    __shared__ bf16 sA[2][128 * 32];
    __shared__ bf16 sB[2][128 * 32];
    int tid = threadIdx.x, lane = tid & 63, wid = tid >> 6;
    int m0 = blockIdx.y * 128, n0 = blockIdx.x * 128;
    int srow = wid * 32 + (lane >> 2);
    int scol = (lane & 3) * 8;
    const bf16* Ag = A + (size_t)(m0 + srow) * Kd + scol;
    const bf16* Wg = W + (size_t)(n0 + srow) * Kd + scol;
    int soff = srow * 32 + scol;
    int wm = (wid & 1) * 64, wn = (wid >> 1) * 64;
    int lcol = lane & 15, quad = lane >> 4;
    f32x4 acc[4][4] = {};
#define STG_Q(buf, k0_) do { \
        async_load16(Ag + (k0_), &sA[buf][soff]); \
        async_load16(Ag + (k0_) + 16 * Kd, &sA[buf][soff + 512]); \
        async_load16(Wg + (k0_), &sB[buf][soff]); \
        async_load16(Wg + (k0_) + 16 * Kd, &sB[buf][soff + 512]); \
    } while (0)
    STG_Q(0, 0);
    STG_Q(1, 32);
    for (int it = 0; it < 32; ++it) {
        if (it < 31) { WAITCNT_VM(4); } else { WAITCNT_VM(0); }
        __builtin_amdgcn_s_barrier();   // buf[it&1] staged by ALL waves
        CFENCE();
        const bf16* cA = sA[it & 1];
        const bf16* cB = sB[it & 1];
        bf16x8 af[4], bfr[4];
#pragma unroll
        for (int i = 0; i < 4; i++)
            af[i] = *(const bf16x8*)&cA[(wm + i * 16 + lcol) * 32 + quad * 8];
#pragma unroll
        for (int i = 0; i < 4; i++)
            bfr[i] = *(const bf16x8*)&cB[(wn + i * 16 + lcol) * 32 + quad * 8];
#pragma unroll
        for (int i = 0; i < 4; i++)
#pragma unroll
            for (int j = 0; j < 4; j++)
                acc[i][j] = MFMA_BF16(af[i], bfr[j], acc[i][j]);
        CFENCE();
        __builtin_amdgcn_s_barrier();   // all waves done reading buf[it&1]
        if (it + 2 < 32) STG_Q(it & 1, (it + 2) * 32);
    }
#undef STG_Q
#pragma unroll
    for (int j = 0; j < 4; j++) {
        int n = n0 + wn + j * 16 + lcol;
        float bv = bias[n];
        int part = n >> 10, d = n & 1023, h = d >> 6, dd = d & 63;
#pragma unroll
        for (int i = 0; i < 4; i++) {
            int mb = m0 + wm + i * 16 + quad * 4;
            int b = mb >> 10, s = mb & 1023;
            if (part == 2) {
                bf16x4 v4;
#pragma unroll
                for (int r = 0; r < 4; r++) v4[r] = (bf16)(acc[i][j][r] + bv);
                *(bf16x4*)&Vt[(size_t)((b * 16 + h) * 64 + dd) * 1024 + s] = v4;
            } else {
                float scv = (part == 0) ? 0.125f : 1.0f;
                bf16* dst = (part == 0 ? Qb : Kb) + (size_t)((b * 16 + h) * 1024 + s) * 64 + dd;
#pragma unroll
                for (int r = 0; r < 4; r++) dst[(size_t)r * 64] = (bf16)((acc[i][j][r] + bv) * scv);
            }
        }
    }
}

// ---------------- out-proj GEMM: 64x128 tile (512 blocks = 2/CU), counted-vmcnt 2-deep ----------------
// 3 async loads/thread per K-step (A:1, B:2) -> steady wait vmcnt(3).
__global__ __launch_bounds__(256) void gemm_out_kernel(
    const bf16* __restrict__ A, const bf16* __restrict__ W,
    const float* __restrict__ bias, float* __restrict__ out)
{
    const int Kd = 1024;
    __shared__ bf16 sA[2][64 * 32];
    __shared__ bf16 sB[2][128 * 32];
    int tid = threadIdx.x, lane = tid & 63, wid = tid >> 6;
    int m0 = blockIdx.y * 64, n0 = blockIdx.x * 128;
    int ra = tid >> 2;              // 0..63
    int scol = (tid & 3) * 8;
    const bf16* Ag = A + (size_t)(m0 + ra) * Kd + scol;
    const bf16* Wg = W + (size_t)(n0 + ra) * Kd + scol;
    int aoff = ra * 32 + scol;
    int wm = (wid & 1) * 32, wn = (wid >> 1) * 64;
    int lcol = lane & 15, quad = lane >> 4;
    f32x4 acc[2][4] = {};
#define STG_O(buf, k0_) do { \
        async_load16(Ag + (k0_), &sA[buf][aoff]); \
        async_load16(Wg + (k0_), &sB[buf][aoff]); \
        async_load16(Wg + (k0_) + 64 * Kd, &sB[buf][aoff + 64 * 32]); \
    } while (0)
    STG_O(0, 0);
    STG_O(1, 32);
    for (int it = 0; it < 32; ++it) {
        if (it < 31) { WAITCNT_VM(3); } else { WAITCNT_VM(0); }
        __builtin_amdgcn_s_barrier();
        CFENCE();
        const bf16* cA = sA[it & 1];
        const bf16* cB = sB[it & 1];
        bf16x8 af[2], bfr[4];
#pragma unroll
        for (int i = 0; i < 2; i++)
            af[i] = *(const bf16x8*)&cA[(wm + i * 16 + lcol) * 32 + quad * 8];
#pragma unroll
        for (int j = 0; j < 4; j++)
            bfr[j] = *(const bf16x8*)&cB[(wn + j * 16 + lcol) * 32 + quad * 8];
#pragma unroll
        for (int i = 0; i < 2; i++)
#pragma unroll
            for (int j = 0; j < 4; j++)
                acc[i][j] = MFMA_BF16(af[i], bfr[j], acc[i][j]);
        CFENCE();
        __builtin_amdgcn_s_barrier();
        if (it + 2 < 32) STG_O(it & 1, (it + 2) * 32);
    }
#undef STG_O
#pragma unroll
    for (int j = 0; j < 4; j++) {
        int n = n0 + wn + j * 16 + lcol;
        float bv = bias[n];
#pragma unroll
        for (int i = 0; i < 2; i++) {
            int m = m0 + wm + i * 16 + quad * 4;
#pragma unroll
            for (int r = 0; r < 4; r++) out[(size_t)(m + r) * 1024 + n] = acc[i][j][r] + bv;
        }
    }
}

// ---------------- flash attention: dbuf K/V + XOR bank swizzle + XCD-aware block swizzle ----------------
// T1: nwg=1024, 8 XCDs. orig = (id&7)*128 + id>>3 puts all 16 q-tiles of one (b,h)
// on ONE XCD -> K/V panels (128KB/head) become L2-resident instead of being
// re-fetched by all 8 XCDs (FETCH_SIZE was ~3x ideal).
__global__ __launch_bounds__(256) void flash_kernel(
    const bf16* __restrict__ Qb, const bf16* __restrict__ Kb, const bf16* __restrict__ Vt,
    bf16* __restrict__ ctx, float* __restrict__ ml)
{
    __shared__ bf16 sK[2][64 * 64];     // [buf][key][d], chunk-swizzled
    __shared__ bf16 sV[2][64 * 64];     // [buf][d][key], chunk-swizzled
    __shared__ bf16 pt[4][16 * 64];     // per-wave 16q x 64k transpose tile, XOR-swizzled
    int tid = threadIdx.x, lane = tid & 63, wid = tid >> 6;
    int bx = blockIdx.x;
    int orig = (bx & 7) * 128 + (bx >> 3);   // XCD-contiguous remap (bijective, 1024 % 8 == 0)
    int qt = orig & 15;
    int h = (orig >> 4) & 15;
    int b = orig >> 8;
    int lcol = lane & 15, quad = lane >> 4;
    size_t base = (size_t)(b * 16 + h) * 65536;

    int q0 = qt * 64 + wid * 16;
    const bf16* qp = Qb + base + (size_t)(q0 + lcol) * 64 + quad * 8;
    bf16x8 a0 = *(const bf16x8*)qp;
    bf16x8 a1 = *(const bf16x8*)(qp + 32);

    char* wpt = (char*)&pt[wid][0];
    int rr8 = lane >> 3;                 // 0..7 (row within 8-row staging group)
    int pp  = lane & 7;                  // physical chunk
    int jj  = pp ^ rr8;                  // logical chunk (swizzle key = row & 7 = rr8)
    int sr0 = wid * 16 + rr8;            // staged row (rows sr0, sr0+8; (+8)&7 preserved)
    int sw  = lcol & 7;                  // read-side swizzle key

#define STAGE_KV(buf, kt_) do { \
        async_load16(Kb + base + (size_t)((kt_) * 64 + sr0) * 64 + jj * 8,       &sK[buf][sr0 * 64 + pp * 8]); \
        async_load16(Kb + base + (size_t)((kt_) * 64 + sr0 + 8) * 64 + jj * 8,   &sK[buf][(sr0 + 8) * 64 + pp * 8]); \
        async_load16(Vt + base + (size_t)sr0 * 1024 + (kt_) * 64 + jj * 8,       &sV[buf][sr0 * 64 + pp * 8]); \
        async_load16(Vt + base + (size_t)(sr0 + 8) * 1024 + (kt_) * 64 + jj * 8, &sV[buf][(sr0 + 8) * 64 + pp * 8]); \
    } while (0)

    float l_[4] = {0.f, 0.f, 0.f, 0.f};
    f32x4 o[4] = {};

    STAGE_KV(0, 0);
    int cur = 0;
    for (int kt = 0; kt < 16; kt++) {
        __syncthreads();                 // buf[cur] ready; prior consumers of buf[cur^1] done
        if (kt < 15) STAGE_KV(cur ^ 1, kt + 1);
        const bf16* sKc = &sK[cur][0];
        const bf16* sVc = &sV[cur][0];
#pragma unroll
        for (int nt = 0; nt < 4; nt++) {
            int ck = quad ^ sw;
            bf16x8 bk0 = *(const bf16x8*)&sKc[(nt * 16 + lcol) * 64 + ck * 8];
            bf16x8 bk1 = *(const bf16x8*)&sKc[(nt * 16 + lcol) * 64 + (ck ^ 4) * 8];
            f32x4 s = {};
            s = MFMA_BF16(a0, bk0, s);
            s = MFMA_BF16(a1, bk1, s);
#pragma unroll
            for (int rr = 0; rr < 4; rr++) {
                float p = __expf(s[rr]);
                l_[rr] += p;
                int row = quad * 4 + rr;
                *(bf16*)(wpt + row * 128 + ((nt * 32 + lcol * 2) ^ ((row & 7) << 4))) = (bf16)p;
            }
        }
#pragma unroll
        for (int kf = 0; kf < 2; kf++) {
            bf16x8 pa = *(const bf16x8*)(wpt + lcol * 128 + (((kf * 4 + quad) ^ sw) << 4));
#pragma unroll
            for (int dt = 0; dt < 4; dt++) {
                bf16x8 vb = *(const bf16x8*)&sVc[(dt * 16 + lcol) * 64 + ((kf * 4 + quad) ^ sw) * 8];
                o[dt] = MFMA_BF16(pa, vb, o[dt]);
            }
        }
        cur ^= 1;
    }
#undef STAGE_KV
#pragma unroll
    for (int mk = 1; mk < 16; mk <<= 1)
#pragma unroll
        for (int rr = 0; rr < 4; rr++) l_[rr] += __shfl_xor(l_[rr], mk, 64);
#pragma unroll
    for (int rr = 0; rr < 4; rr++) {
        float inv = 1.f / l_[rr];
        int qg = q0 + quad * 4 + rr;
#pragma unroll
        for (int dt = 0; dt < 4; dt++)
            ctx[(size_t)(b * 1024 + qg) * 1024 + h * 64 + dt * 16 + lcol] = (bf16)(o[dt][rr] * inv);
        if (lcol == 0)
            ml[(size_t)(b * 16 + h) * 1024 + qg] = l_[rr];
    }
}

// ---------------- attn-weights: dbuf K staging + XOR swizzle + XCD-aware block swizzle ----------------
// T1: same remap; each XCD gets 128 consecutive origs = 8 full qt-groups of one batch
// -> Q rows and K tiles reused within one XCD's L2.
__global__ __launch_bounds__(256) void aw_kernel(
    const bf16* __restrict__ Qb, const bf16* __restrict__ Kb,
    const float* __restrict__ ml, float* __restrict__ aw)
{
    __shared__ bf16 sK[2][64 * 64];   // [buf][key][d], chunk-swizzled
    int tid = threadIdx.x, lane = tid & 63, wid = tid >> 6;
    int bx = blockIdx.x;
    int orig = (bx & 7) * 128 + (bx >> 3);
    int kt = orig & 15;
    int qt = (orig >> 4) & 15;
    int b = orig >> 8;
    int lcol = lane & 15, quad = lane >> 4;
    int q0 = qt * 64 + wid * 16;
    int kbase = kt * 64;
    int sw = lcol & 7;
    // staging geometry (two 16B chunks per thread)
    int r0_ = tid >> 3, p0_ = tid & 7, j0_ = p0_ ^ (r0_ & 7);
    int r1_ = (tid + 256) >> 3, p1_ = (tid + 256) & 7, j1_ = p1_ ^ (r1_ & 7);

#define STAGE_K(buf, hh) do { \
        size_t hb_ = (size_t)(b * 16 + (hh)) * 65536; \
        async_load16(Kb + hb_ + (size_t)(kbase + r0_) * 64 + j0_ * 8, &sK[buf][(size_t)tid * 8]); \
        async_load16(Kb + hb_ + (size_t)(kbase + r1_) * 64 + j1_ * 8, &sK[buf][(size_t)(tid + 256) * 8]); \
    } while (0)

    float acc[16];
#pragma unroll
    for (int i = 0; i < 16; i++) acc[i] = 0.f;

    STAGE_K(0, 0);
    int cur = 0;
    for (int h = 0; h < 16; h++) {
        size_t base = (size_t)(b * 16 + h) * 65536;
        const bf16* qp = Qb + base + (size_t)(q0 + lcol) * 64 + quad * 8;
        bf16x8 a0 = *(const bf16x8*)qp;
        bf16x8 a1 = *(const bf16x8*)(qp + 32);
        float scale[4];
#pragma unroll
        for (int rr = 0; rr < 4; rr++)
            scale[rr] = 0.0625f / ml[(size_t)(b * 16 + h) * 1024 + q0 + quad * 4 + rr];
        __syncthreads();                 // sK[cur] staged; prior consumers of sK[cur^1] done
        if (h < 15) STAGE_K(cur ^ 1, h + 1);
#pragma unroll
        for (int nt = 0; nt < 4; nt++) {
            int ck = quad ^ sw;
            bf16x8 bk0 = *(const bf16x8*)&sK[cur][(nt * 16 + lcol) * 64 + ck * 8];
            bf16x8 bk1 = *(const bf16x8*)&sK[cur][(nt * 16 + lcol) * 64 + (ck ^ 4) * 8];
            f32x4 s = {};
            s = MFMA_BF16(a0, bk0, s);
            s = MFMA_BF16(a1, bk1, s);
#pragma unroll
            for (int rr = 0; rr < 4; rr++)
                acc[nt * 4 + rr] += __expf(s[rr]) * scale[rr];
        }
        cur ^= 1;
    }
#undef STAGE_K
#pragma unroll
    for (int nt = 0; nt < 4; nt++)
#pragma unroll
        for (int rr = 0; rr < 4; rr++)
            aw[(size_t)(b * 1024 + q0 + quad * 4 + rr) * 1024 + kbase + nt * 16 + lcol] = acc[nt * 4 + rr];
}

// ---------------- residual + LayerNorm (fp32 output) ----------------
__global__ __launch_bounds__(256) void ln_kernel(
    const float* __restrict__ x, const float* __restrict__ ao,
    const float* __restrict__ w, const float* __restrict__ bsh,
    float* __restrict__ y)
{
    int row = blockIdx.x, tid = threadIdx.x;
    float4 xv = ((const float4*)(x + (size_t)row * 1024))[tid];
    float4 av = ((const float4*)(ao + (size_t)row * 1024))[tid];
    float4 v = {xv.x + av.x, xv.y + av.y, xv.z + av.z, xv.w + av.w};
    float s = v.x + v.y + v.z + v.w;
    float ss = v.x * v.x + v.y * v.y + v.z * v.z + v.w * v.w;
#pragma unroll
    for (int off = 32; off; off >>= 1) { s += __shfl_down(s, off); ss += __shfl_down(ss, off); }
    __shared__ float rs[4], rss[4];
    int lane = tid & 63, wid = tid >> 6;
    if (lane == 0) { rs[wid] = s; rss[wid] = ss; }
    __syncthreads();
    s = rs[0] + rs[1] + rs[2] + rs[3];
    ss = rss[0] + rss[1] + rss[2] + rss[3];
    float mean = s * (1.f / 1024.f);
    float var = ss * (1.f / 1024.f) - mean * mean;
    float inv = rsqrtf(var + 1e-5f);
    float4 wv = ((const float4*)w)[tid];
    float4 bv = ((const float4*)bsh)[tid];
    float4 o;
    o.x = (v.x - mean) * inv * wv.x + bv.x;
    o.y = (v.y - mean) * inv * wv.y + bv.y;
    o.z = (v.z - mean) * inv * wv.z + bv.z;
    o.w = (v.w - mean) * inv * wv.w + bv.w;
    ((float4*)y)[row * 256 + tid] = o;
}

extern "C" void kernel_launch(void* const* d_in, const int* in_sizes, int n_in,
                              void* d_out, int out_size, void* d_ws, size_t ws_size,
                              hipStream_t stream) {
    const float* x     = (const float*)d_in[0];
    const float* w_qkv = (const float*)d_in[1];
    const float* b_qkv = (const float*)d_in[2];
    const float* w_out = (const float*)d_in[3];
    const float* b_out = (const float*)d_in[4];
    const float* ln_w  = (const float*)d_in[5];
    const float* ln_b  = (const float*)d_in[6];

    char* ws = (char*)d_ws;
    // [0,8M) Qb | [8,16M) Kb | [16,24M) Vt | [24,32M) ctx | [32,32.25M) ml(l, fp32) |
    // x_bf [33,41M), wq_bf [41,47M) live only until gemm_qkv;
    // wo_bf [16,18M) after aw (Vt dead); ao fp32 [0,16M) after aw (Qb/Kb dead).
    bf16*   Qb    = (bf16*)(ws);
    bf16*   Kb    = (bf16*)(ws + (8ull  << 20));
    bf16*   Vt    = (bf16*)(ws + (16ull << 20));
    bf16*   ctx   = (bf16*)(ws + (24ull << 20));
    float*  ml    = (float*)(ws + (32ull << 20));
    bf16*   x_bf  = (bf16*)(ws + (33ull << 20));
    bf16*   wq_bf = (bf16*)(ws + (41ull << 20));
    bf16*   wo_bf = (bf16*)(ws + (16ull << 20));
    float*  ao    = (float*)(ws);

    float* y_out  = (float*)d_out;
    float* aw_out = y_out + 4ull * 1024 * 1024;

    cvt_kernel<<<4096, 256, 0, stream>>>(x, x_bf, 1048576);
    cvt_kernel<<<3072, 256, 0, stream>>>(w_qkv, wq_bf, 786432);
    gemm_qkv_kernel<<<dim3(24, 32), 256, 0, stream>>>(x_bf, wq_bf, b_qkv, Qb, Kb, Vt);
    flash_kernel<<<1024, 256, 0, stream>>>(Qb, Kb, Vt, ctx, ml);
    aw_kernel<<<1024, 256, 0, stream>>>(Qb, Kb, ml, aw_out);
    cvt_kernel<<<1024, 256, 0, stream>>>(w_out, wo_bf, 262144);
    gemm_out_kernel<<<dim3(8, 64), 256, 0, stream>>>(ctx, wo_bf, b_out, ao);
    ln_kernel<<<4096, 256, 0, stream>>>(x, ao, ln_w, ln_b, y_out);
}

// Round 3
// 219.510 us; speedup vs baseline: 1.0086x; 1.0086x over previous
//
#include <hip/hip_runtime.h>
#include <cstdint>

typedef __bf16 bf16;
typedef __bf16 bf16x8 __attribute__((ext_vector_type(8)));
typedef __bf16 bf16x4 __attribute__((ext_vector_type(4)));
typedef float  f32x4  __attribute__((ext_vector_type(4)));

#define MFMA_BF16(a, b, c) __builtin_amdgcn_mfma_f32_16x16x32_bf16(a, b, c, 0, 0, 0)

// counted vmcnt wait (T4): leave N loads in flight; "memory" clobber fences
// compiler-managed LDS reads from moving above it.
#define WAITCNT_VM(n) asm volatile("s_waitcnt vmcnt(" #n ")" ::: "memory")
#define CFENCE()      asm volatile("" ::: "memory")

// async global->LDS, 16B/lane; LDS dest affine in lane (base + lane*16).
__device__ __forceinline__ void async_load16(const void* g, void* l) {
    __builtin_amdgcn_global_load_lds(
        (__attribute__((address_space(1))) uint32_t*)(uintptr_t)g,
        (__attribute__((address_space(3))) uint32_t*)(uint32_t)(uintptr_t)l,
        16, 0, 0);
}

// ---------------- fp32 -> bf16 convert ----------------
__global__ void cvt_kernel(const float* __restrict__ src, bf16* __restrict__ dst, int n4) {
    int i = blockIdx.x * blockDim.x + threadIdx.x;
    if (i < n4) {
        float4 v = ((const float4*)src)[i];
        bf16x4 o;
        o[0] = (bf16)v.x; o[1] = (bf16)v.y; o[2] = (bf16)v.z; o[3] = (bf16)v.w;
        ((bf16x4*)dst)[i] = o;
    }
}

// ---------------- QKV GEMM: counted-vmcnt 2-deep pipeline + T2 LDS chunk swizzle ----------------
// K-tile rows are 64B (32 bf16): an unswizzled b128 fragment read is an 8-way bank
// conflict (rows r,r+2 alias; SQ_LDS_BANK_CONFLICT was 3.1M). Swizzle key (row>>1)&3
// makes the 16B-phase (4r + chunk) mod 8 cover all 8 phases -> 2-way (free).
// Staging keeps LDS dest linear (global_load_lds constraint) and pre-swizzles the
// GLOBAL source chunk: j = p ^ ((row>>1)&3); both +0/+16-row loads share the key.
__global__ __launch_bounds__(256) void gemm_qkv_kernel(
    const bf16* __restrict__ A, const bf16* __restrict__ W,
    const float* __restrict__ bias,
    bf16* __restrict__ Qb, bf16* __restrict__ Kb, bf16* __restrict__ Vt)
{
    const int Kd = 1024;
    __shared__ bf16 sA[2][128 * 32];
    __shared__ bf16 sB[2][128 * 32];
    int tid = threadIdx.x, lane = tid & 63, wid = tid >> 6;
    int m0 = blockIdx.y * 128, n0 = blockIdx.x * 128;
    int srow = wid * 32 + (lane >> 2);
    int pchunk = lane & 3;                       // physical chunk (LDS dest, linear)
    int jchunk = pchunk ^ ((lane >> 3) & 3);     // logical chunk (global source); key=(srow>>1)&3
    const bf16* Ag = A + (size_t)(m0 + srow) * Kd + jchunk * 8;
    const bf16* Wg = W + (size_t)(n0 + srow) * Kd + jchunk * 8;
    int soff = srow * 32 + pchunk * 8;
    int wm = (wid & 1) * 64, wn = (wid >> 1) * 64;
    int lcol = lane & 15, quad = lane >> 4;
    int ckey = (lcol >> 1) & 3;                  // read-side swizzle key (rows ≡ lcol mod 16)
    f32x4 acc[4][4] = {};
#define STG_Q(buf, k0_) do { \
        async_load16(Ag + (k0_), &sA[buf][soff]); \
        async_load16(Ag + (k0_) + 16 * Kd, &sA[buf][soff + 512]); \
        async_load16(Wg + (k0_), &sB[buf][soff]); \
        async_load16(Wg + (k0_) + 16 * Kd, &sB[buf][soff + 512]); \
    } while (0)
    STG_Q(0, 0);
    STG_Q(1, 32);
    for (int it = 0; it < 32; ++it) {
        if (it < 31) { WAITCNT_VM(4); } else { WAITCNT_VM(0); }
        __builtin_amdgcn_s_barrier();   // buf[it&1] staged by ALL waves
        CFENCE();
        const bf16* cA = sA[it & 1];
        const bf16* cB = sB[it & 1];
        bf16x8 af[4], bfr[4];
#pragma unroll
        for (int i = 0; i < 4; i++)
            af[i] = *(const bf16x8*)&cA[(wm + i * 16 + lcol) * 32 + (quad ^ ckey) * 8];
#pragma unroll
        for (int i = 0; i < 4; i++)
            bfr[i] = *(const bf16x8*)&cB[(wn + i * 16 + lcol) * 32 + (quad ^ ckey) * 8];
#pragma unroll
        for (int i = 0; i < 4; i++)
#pragma unroll
            for (int j = 0; j < 4; j++)
                acc[i][j] = MFMA_BF16(af[i], bfr[j], acc[i][j]);
        CFENCE();
        __builtin_amdgcn_s_barrier();   // all waves done reading buf[it&1]
        if (it + 2 < 32) STG_Q(it & 1, (it + 2) * 32);
    }
#undef STG_Q
#pragma unroll
    for (int j = 0; j < 4; j++) {
        int n = n0 + wn + j * 16 + lcol;
        float bv = bias[n];
        int part = n >> 10, d = n & 1023, h = d >> 6, dd = d & 63;
#pragma unroll
        for (int i = 0; i < 4; i++) {
            int mb = m0 + wm + i * 16 + quad * 4;
            int b = mb >> 10, s = mb & 1023;
            if (part == 2) {
                bf16x4 v4;
#pragma unroll
                for (int r = 0; r < 4; r++) v4[r] = (bf16)(acc[i][j][r] + bv);
                *(bf16x4*)&Vt[(size_t)((b * 16 + h) * 64 + dd) * 1024 + s] = v4;
            } else {
                float scv = (part == 0) ? 0.125f : 1.0f;
                bf16* dst = (part == 0 ? Qb : Kb) + (size_t)((b * 16 + h) * 1024 + s) * 64 + dd;
#pragma unroll
                for (int r = 0; r < 4; r++) dst[(size_t)r * 64] = (bf16)((acc[i][j][r] + bv) * scv);
            }
        }
    }
}

// ---------------- out-proj GEMM: 64x128 tile, counted-vmcnt 2-deep + T2 chunk swizzle ----------------
__global__ __launch_bounds__(256) void gemm_out_kernel(
    const bf16* __restrict__ A, const bf16* __restrict__ W,
    const float* __restrict__ bias, float* __restrict__ out)
{
    const int Kd = 1024;
    __shared__ bf16 sA[2][64 * 32];
    __shared__ bf16 sB[2][128 * 32];
    int tid = threadIdx.x, lane = tid & 63, wid = tid >> 6;
    int m0 = blockIdx.y * 64, n0 = blockIdx.x * 128;
    int ra = tid >> 2;                            // 0..63
    int pchunk = tid & 3;                         // physical chunk (LDS dest, linear)
    int jchunk = pchunk ^ ((tid >> 3) & 3);       // logical chunk (source); key=(ra>>1)&3
    const bf16* Ag = A + (size_t)(m0 + ra) * Kd + jchunk * 8;
    const bf16* Wg = W + (size_t)(n0 + ra) * Kd + jchunk * 8;
    int aoff = ra * 32 + pchunk * 8;
    int wm = (wid & 1) * 32, wn = (wid >> 1) * 64;
    int lcol = lane & 15, quad = lane >> 4;
    int ckey = (lcol >> 1) & 3;
    f32x4 acc[2][4] = {};
#define STG_O(buf, k0_) do { \
        async_load16(Ag + (k0_), &sA[buf][aoff]); \
        async_load16(Wg + (k0_), &sB[buf][aoff]); \
        async_load16(Wg + (k0_) + 64 * Kd, &sB[buf][aoff + 64 * 32]); \
    } while (0)
    STG_O(0, 0);
    STG_O(1, 32);
    for (int it = 0; it < 32; ++it) {
        if (it < 31) { WAITCNT_VM(3); } else { WAITCNT_VM(0); }
        __builtin_amdgcn_s_barrier();
        CFENCE();
        const bf16* cA = sA[it & 1];
        const bf16* cB = sB[it & 1];
        bf16x8 af[2], bfr[4];
#pragma unroll
        for (int i = 0; i < 2; i++)
            af[i] = *(const bf16x8*)&cA[(wm + i * 16 + lcol) * 32 + (quad ^ ckey) * 8];
#pragma unroll
        for (int j = 0; j < 4; j++)
            bfr[j] = *(const bf16x8*)&cB[(wn + j * 16 + lcol) * 32 + (quad ^ ckey) * 8];
#pragma unroll
        for (int i = 0; i < 2; i++)
#pragma unroll
            for (int j = 0; j < 4; j++)
                acc[i][j] = MFMA_BF16(af[i], bfr[j], acc[i][j]);
        CFENCE();
        __builtin_amdgcn_s_barrier();
        if (it + 2 < 32) STG_O(it & 1, (it + 2) * 32);
    }
#undef STG_O
#pragma unroll
    for (int j = 0; j < 4; j++) {
        int n = n0 + wn + j * 16 + lcol;
        float bv = bias[n];
#pragma unroll
        for (int i = 0; i < 2; i++) {
            int m = m0 + wm + i * 16 + quad * 4;
#pragma unroll
            for (int r = 0; r < 4; r++) out[(size_t)(m + r) * 1024 + n] = acc[i][j][r] + bv;
        }
    }
}

// ---------------- flash attention: dbuf K/V + XOR bank swizzle + XCD-aware block swizzle ----------------
// T1: nwg=1024, 8 XCDs. orig = (id&7)*128 + id>>3 puts all 16 q-tiles of one (b,h)
// on ONE XCD -> K/V panels (128KB/head) become L2-resident instead of being
// re-fetched by all 8 XCDs.
__global__ __launch_bounds__(256) void flash_kernel(
    const bf16* __restrict__ Qb, const bf16* __restrict__ Kb, const bf16* __restrict__ Vt,
    bf16* __restrict__ ctx, float* __restrict__ ml)
{
    __shared__ bf16 sK[2][64 * 64];     // [buf][key][d], chunk-swizzled
    __shared__ bf16 sV[2][64 * 64];     // [buf][d][key], chunk-swizzled
    __shared__ bf16 pt[4][16 * 64];     // per-wave 16q x 64k transpose tile, XOR-swizzled
    int tid = threadIdx.x, lane = tid & 63, wid = tid >> 6;
    int bx = blockIdx.x;
    int orig = (bx & 7) * 128 + (bx >> 3);   // XCD-contiguous remap (bijective, 1024 % 8 == 0)
    int qt = orig & 15;
    int h = (orig >> 4) & 15;
    int b = orig >> 8;
    int lcol = lane & 15, quad = lane >> 4;
    size_t base = (size_t)(b * 16 + h) * 65536;

    int q0 = qt * 64 + wid * 16;
    const bf16* qp = Qb + base + (size_t)(q0 + lcol) * 64 + quad * 8;
    bf16x8 a0 = *(const bf16x8*)qp;
    bf16x8 a1 = *(const bf16x8*)(qp + 32);

    char* wpt = (char*)&pt[wid][0];
    int rr8 = lane >> 3;                 // 0..7 (row within 8-row staging group)
    int pp  = lane & 7;                  // physical chunk
    int jj  = pp ^ rr8;                  // logical chunk (swizzle key = row & 7 = rr8)
    int sr0 = wid * 16 + rr8;            // staged row (rows sr0, sr0+8; (+8)&7 preserved)
    int sw  = lcol & 7;                  // read-side swizzle key

#define STAGE_KV(buf, kt_) do { \
        async_load16(Kb + base + (size_t)((kt_) * 64 + sr0) * 64 + jj * 8,       &sK[buf][sr0 * 64 + pp * 8]); \
        async_load16(Kb + base + (size_t)((kt_) * 64 + sr0 + 8) * 64 + jj * 8,   &sK[buf][(sr0 + 8) * 64 + pp * 8]); \
        async_load16(Vt + base + (size_t)sr0 * 1024 + (kt_) * 64 + jj * 8,       &sV[buf][sr0 * 64 + pp * 8]); \
        async_load16(Vt + base + (size_t)(sr0 + 8) * 1024 + (kt_) * 64 + jj * 8, &sV[buf][(sr0 + 8) * 64 + pp * 8]); \
    } while (0)

    float l_[4] = {0.f, 0.f, 0.f, 0.f};
    f32x4 o[4] = {};

    STAGE_KV(0, 0);
    int cur = 0;
    for (int kt = 0; kt < 16; kt++) {
        __syncthreads();                 // buf[cur] ready; prior consumers of buf[cur^1] done
        if (kt < 15) STAGE_KV(cur ^ 1, kt + 1);
        const bf16* sKc = &sK[cur][0];
        const bf16* sVc = &sV[cur][0];
#pragma unroll
        for (int nt = 0; nt < 4; nt++) {
            int ck = quad ^ sw;
            bf16x8 bk0 = *(const bf16x8*)&sKc[(nt * 16 + lcol) * 64 + ck * 8];
            bf16x8 bk1 = *(const bf16x8*)&sKc[(nt * 16 + lcol) * 64 + (ck ^ 4) * 8];
            f32x4 s = {};
            s = MFMA_BF16(a0, bk0, s);
            s = MFMA_BF16(a1, bk1, s);
#pragma unroll
            for (int rr = 0; rr < 4; rr++) {
                float p = __expf(s[rr]);
                l_[rr] += p;
                int row = quad * 4 + rr;
                *(bf16*)(wpt + row * 128 + ((nt * 32 + lcol * 2) ^ ((row & 7) << 4))) = (bf16)p;
            }
        }
#pragma unroll
        for (int kf = 0; kf < 2; kf++) {
            bf16x8 pa = *(const bf16x8*)(wpt + lcol * 128 + (((kf * 4 + quad) ^ sw) << 4));
#pragma unroll
            for (int dt = 0; dt < 4; dt++) {
                bf16x8 vb = *(const bf16x8*)&sVc[(dt * 16 + lcol) * 64 + ((kf * 4 + quad) ^ sw) * 8];
                o[dt] = MFMA_BF16(pa, vb, o[dt]);
            }
        }
        cur ^= 1;
    }
#undef STAGE_KV
#pragma unroll
    for (int mk = 1; mk < 16; mk <<= 1)
#pragma unroll
        for (int rr = 0; rr < 4; rr++) l_[rr] += __shfl_xor(l_[rr], mk, 64);
#pragma unroll
    for (int rr = 0; rr < 4; rr++) {
        float inv = 1.f / l_[rr];
        int qg = q0 + quad * 4 + rr;
#pragma unroll
        for (int dt = 0; dt < 4; dt++)
            ctx[(size_t)(b * 1024 + qg) * 1024 + h * 64 + dt * 16 + lcol] = (bf16)(o[dt][rr] * inv);
        if (lcol == 0)
            ml[(size_t)(b * 16 + h) * 1024 + qg] = l_[rr];
    }
}

// ---------------- attn-weights: dbuf K staging + XOR swizzle + XCD-aware block swizzle ----------------
__global__ __launch_bounds__(256) void aw_kernel(
    const bf16* __restrict__ Qb, const bf16* __restrict__ Kb,
    const float* __restrict__ ml, float* __restrict__ aw)
{
    __shared__ bf16 sK[2][64 * 64];   // [buf][key][d], chunk-swizzled
    int tid = threadIdx.x, lane = tid & 63, wid = tid >> 6;
    int bx = blockIdx.x;
    int orig = (bx & 7) * 128 + (bx >> 3);
    int kt = orig & 15;
    int qt = (orig >> 4) & 15;
    int b = orig >> 8;
    int lcol = lane & 15, quad = lane >> 4;
    int q0 = qt * 64 + wid * 16;
    int kbase = kt * 64;
    int sw = lcol & 7;
    // staging geometry (two 16B chunks per thread)
    int r0_ = tid >> 3, p0_ = tid & 7, j0_ = p0_ ^ (r0_ & 7);
    int r1_ = (tid + 256) >> 3, p1_ = (tid + 256) & 7, j1_ = p1_ ^ (r1_ & 7);

#define STAGE_K(buf, hh) do { \
        size_t hb_ = (size_t)(b * 16 + (hh)) * 65536; \
        async_load16(Kb + hb_ + (size_t)(kbase + r0_) * 64 + j0_ * 8, &sK[buf][(size_t)tid * 8]); \
        async_load16(Kb + hb_ + (size_t)(kbase + r1_) * 64 + j1_ * 8, &sK[buf][(size_t)(tid + 256) * 8]); \
    } while (0)

    float acc[16];
#pragma unroll
    for (int i = 0; i < 16; i++) acc[i] = 0.f;

    STAGE_K(0, 0);
    int cur = 0;
    for (int h = 0; h < 16; h++) {
        size_t base = (size_t)(b * 16 + h) * 65536;
        const bf16* qp = Qb + base + (size_t)(q0 + lcol) * 64 + quad * 8;
        bf16x8 a0 = *(const bf16x8*)qp;
        bf16x8 a1 = *(const bf16x8*)(qp + 32);
        float scale[4];
#pragma unroll
        for (int rr = 0; rr < 4; rr++)
            scale[rr] = 0.0625f / ml[(size_t)(b * 16 + h) * 1024 + q0 + quad * 4 + rr];
        __syncthreads();                 // sK[cur] staged; prior consumers of sK[cur^1] done
        if (h < 15) STAGE_K(cur ^ 1, h + 1);
#pragma unroll
        for (int nt = 0; nt < 4; nt++) {
            int ck = quad ^ sw;
            bf16x8 bk0 = *(const bf16x8*)&sK[cur][(nt * 16 + lcol) * 64 + ck * 8];
            bf16x8 bk1 = *(const bf16x8*)&sK[cur][(nt * 16 + lcol) * 64 + (ck ^ 4) * 8];
            f32x4 s = {};
            s = MFMA_BF16(a0, bk0, s);
            s = MFMA_BF16(a1, bk1, s);
#pragma unroll
            for (int rr = 0; rr < 4; rr++)
                acc[nt * 4 + rr] += __expf(s[rr]) * scale[rr];
        }
        cur ^= 1;
    }
#undef STAGE_K
#pragma unroll
    for (int nt = 0; nt < 4; nt++)
#pragma unroll
        for (int rr = 0; rr < 4; rr++)
            aw[(size_t)(b * 1024 + q0 + quad * 4 + rr) * 1024 + kbase + nt * 16 + lcol] = acc[nt * 4 + rr];
}

// ---------------- residual + LayerNorm (fp32 output) ----------------
__global__ __launch_bounds__(256) void ln_kernel(
    const float* __restrict__ x, const float* __restrict__ ao,
    const float* __restrict__ w, const float* __restrict__ bsh,
    float* __restrict__ y)
{
    int row = blockIdx.x, tid = threadIdx.x;
    float4 xv = ((const float4*)(x + (size_t)row * 1024))[tid];
    float4 av = ((const float4*)(ao + (size_t)row * 1024))[tid];
    float4 v = {xv.x + av.x, xv.y + av.y, xv.z + av.z, xv.w + av.w};
    float s = v.x + v.y + v.z + v.w;
    float ss = v.x * v.x + v.y * v.y + v.z * v.z + v.w * v.w;
#pragma unroll
    for (int off = 32; off; off >>= 1) { s += __shfl_down(s, off); ss += __shfl_down(ss, off); }
    __shared__ float rs[4], rss[4];
    int lane = tid & 63, wid = tid >> 6;
    if (lane == 0) { rs[wid] = s; rss[wid] = ss; }
    __syncthreads();
    s = rs[0] + rs[1] + rs[2] + rs[3];
    ss = rss[0] + rss[1] + rss[2] + rss[3];
    float mean = s * (1.f / 1024.f);
    float var = ss * (1.f / 1024.f) - mean * mean;
    float inv = rsqrtf(var + 1e-5f);
    float4 wv = ((const float4*)w)[tid];
    float4 bv = ((const float4*)bsh)[tid];
    float4 o;
    o.x = (v.x - mean) * inv * wv.x + bv.x;
    o.y = (v.y - mean) * inv * wv.y + bv.y;
    o.z = (v.z - mean) * inv * wv.z + bv.z;
    o.w = (v.w - mean) * inv * wv.w + bv.w;
    ((float4*)y)[row * 256 + tid] = o;
}

extern "C" void kernel_launch(void* const* d_in, const int* in_sizes, int n_in,
                              void* d_out, int out_size, void* d_ws, size_t ws_size,
                              hipStream_t stream) {
    const float* x     = (const float*)d_in[0];
    const float* w_qkv = (const float*)d_in[1];
    const float* b_qkv = (const float*)d_in[2];
    const float* w_out = (const float*)d_in[3];
    const float* b_out = (const float*)d_in[4];
    const float* ln_w  = (const float*)d_in[5];
    const float* ln_b  = (const float*)d_in[6];

    char* ws = (char*)d_ws;
    // [0,8M) Qb | [8,16M) Kb | [16,24M) Vt | [24,32M) ctx | [32,32.25M) ml(l, fp32) |
    // x_bf [33,41M), wq_bf [41,47M) live only until gemm_qkv;
    // wo_bf [16,18M) after aw (Vt dead); ao fp32 [0,16M) after aw (Qb/Kb dead).
    bf16*   Qb    = (bf16*)(ws);
    bf16*   Kb    = (bf16*)(ws + (8ull  << 20));
    bf16*   Vt    = (bf16*)(ws + (16ull << 20));
    bf16*   ctx   = (bf16*)(ws + (24ull << 20));
    float*  ml    = (float*)(ws + (32ull << 20));
    bf16*   x_bf  = (bf16*)(ws + (33ull << 20));
    bf16*   wq_bf = (bf16*)(ws + (41ull << 20));
    bf16*   wo_bf = (bf16*)(ws + (16ull << 20));
    float*  ao    = (float*)(ws);

    float* y_out  = (float*)d_out;
    float* aw_out = y_out + 4ull * 1024 * 1024;

    cvt_kernel<<<4096, 256, 0, stream>>>(x, x_bf, 1048576);
    cvt_kernel<<<3072, 256, 0, stream>>>(w_qkv, wq_bf, 786432);
    gemm_qkv_kernel<<<dim3(24, 32), 256, 0, stream>>>(x_bf, wq_bf, b_qkv, Qb, Kb, Vt);
    flash_kernel<<<1024, 256, 0, stream>>>(Qb, Kb, Vt, ctx, ml);
    aw_kernel<<<1024, 256, 0, stream>>>(Qb, Kb, ml, aw_out);
    cvt_kernel<<<1024, 256, 0, stream>>>(w_out, wo_bf, 262144);
    gemm_out_kernel<<<dim3(8, 64), 256, 0, stream>>>(ctx, wo_bf, b_out, ao);
    ln_kernel<<<4096, 256, 0, stream>>>(x, ao, ln_w, ln_b, y_out);
}

// Round 4
// 218.103 us; speedup vs baseline: 1.0151x; 1.0065x over previous
//
#include <hip/hip_runtime.h>
#include <cstdint>

typedef __bf16 bf16;
typedef __bf16 bf16x8 __attribute__((ext_vector_type(8)));
typedef __bf16 bf16x4 __attribute__((ext_vector_type(4)));
typedef float  f32x4  __attribute__((ext_vector_type(4)));

#define MFMA_BF16(a, b, c) __builtin_amdgcn_mfma_f32_16x16x32_bf16(a, b, c, 0, 0, 0)

// counted vmcnt wait (T4): leave N loads in flight; "memory" clobber fences
// compiler-managed LDS reads from moving above it.
#define WAITCNT_VM(n) asm volatile("s_waitcnt vmcnt(" #n ")" ::: "memory")
#define CFENCE()      asm volatile("" ::: "memory")

// async global->LDS, 16B/lane; LDS dest affine in lane (base + lane*16).
__device__ __forceinline__ void async_load16(const void* g, void* l) {
    __builtin_amdgcn_global_load_lds(
        (__attribute__((address_space(1))) uint32_t*)(uintptr_t)g,
        (__attribute__((address_space(3))) uint32_t*)(uint32_t)(uintptr_t)l,
        16, 0, 0);
}

// ---------------- fp32 -> bf16 convert ----------------
__global__ void cvt_kernel(const float* __restrict__ src, bf16* __restrict__ dst, int n4) {
    int i = blockIdx.x * blockDim.x + threadIdx.x;
    if (i < n4) {
        float4 v = ((const float4*)src)[i];
        bf16x4 o;
        o[0] = (bf16)v.x; o[1] = (bf16)v.y; o[2] = (bf16)v.z; o[3] = (bf16)v.w;
        ((bf16x4*)dst)[i] = o;
    }
}

// ---------------- QKV GEMM: 3-deep counted-vmcnt pipeline + T2 swizzle + T1 XCD remap ----------------
// R3 post-mortem: conflicts 3.1M->0 but time flat -> stall-bound, not LDS-bound.
// 3 LDS buffers (48KB, still 3 blocks/CU): load-issue -> vmcnt-retire window = 2 full
// iterations (~2600cy) > HBM latency (~900cy). Steady wait vmcnt(8) (2 tiles in flight),
// tail 4/0. T1: flat block remap gives each XCD 96 contiguous blocks (4 A-panels).
__global__ __launch_bounds__(256) void gemm_qkv_kernel(
    const bf16* __restrict__ A, const bf16* __restrict__ W,
    const float* __restrict__ bias,
    bf16* __restrict__ Qb, bf16* __restrict__ Kb, bf16* __restrict__ Vt)
{
    const int Kd = 1024;
    __shared__ bf16 sA[3][128 * 32];
    __shared__ bf16 sB[3][128 * 32];
    int tid = threadIdx.x, lane = tid & 63, wid = tid >> 6;
    int flat = blockIdx.y * 24 + blockIdx.x;          // 0..767
    int orig = (flat & 7) * 96 + (flat >> 3);         // XCD-contiguous (768 % 8 == 0)
    int m0 = (orig / 24) * 128, n0 = (orig % 24) * 128;
    int srow = wid * 32 + (lane >> 2);
    int pchunk = lane & 3;                       // physical chunk (LDS dest, linear)
    int jchunk = pchunk ^ ((lane >> 3) & 3);     // logical chunk (source); key=(srow>>1)&3
    const bf16* Ag = A + (size_t)(m0 + srow) * Kd + jchunk * 8;
    const bf16* Wg = W + (size_t)(n0 + srow) * Kd + jchunk * 8;
    int soff = srow * 32 + pchunk * 8;
    int wm = (wid & 1) * 64, wn = (wid >> 1) * 64;
    int lcol = lane & 15, quad = lane >> 4;
    int ckey = (lcol >> 1) & 3;                  // read-side swizzle key
    f32x4 acc[4][4] = {};
#define STG_Q(buf, k0_) do { \
        async_load16(Ag + (k0_), &sA[buf][soff]); \
        async_load16(Ag + (k0_) + 16 * Kd, &sA[buf][soff + 512]); \
        async_load16(Wg + (k0_), &sB[buf][soff]); \
        async_load16(Wg + (k0_) + 16 * Kd, &sB[buf][soff + 512]); \
    } while (0)
    STG_Q(0, 0);
    STG_Q(1, 32);
    STG_Q(2, 64);
    int cur = 0;
    for (int it = 0; it < 32; ++it) {
        if (it < 30)      { WAITCNT_VM(8); }   // tiles it+1, it+2 stay in flight
        else if (it == 30){ WAITCNT_VM(4); }
        else              { WAITCNT_VM(0); }
        __builtin_amdgcn_s_barrier();   // buf[cur] staged by ALL waves
        CFENCE();
        const bf16* cA = sA[cur];
        const bf16* cB = sB[cur];
        bf16x8 af[4], bfr[4];
#pragma unroll
        for (int i = 0; i < 4; i++)
            af[i] = *(const bf16x8*)&cA[(wm + i * 16 + lcol) * 32 + (quad ^ ckey) * 8];
#pragma unroll
        for (int i = 0; i < 4; i++)
            bfr[i] = *(const bf16x8*)&cB[(wn + i * 16 + lcol) * 32 + (quad ^ ckey) * 8];
#pragma unroll
        for (int i = 0; i < 4; i++)
#pragma unroll
            for (int j = 0; j < 4; j++)
                acc[i][j] = MFMA_BF16(af[i], bfr[j], acc[i][j]);
        CFENCE();
        __builtin_amdgcn_s_barrier();   // all waves done reading buf[cur]
        if (it + 3 < 32) STG_Q(cur, (it + 3) * 32);   // refill the buffer just consumed
        cur = (cur == 2) ? 0 : cur + 1;
    }
#undef STG_Q
#pragma unroll
    for (int j = 0; j < 4; j++) {
        int n = n0 + wn + j * 16 + lcol;
        float bv = bias[n];
        int part = n >> 10, d = n & 1023, h = d >> 6, dd = d & 63;
#pragma unroll
        for (int i = 0; i < 4; i++) {
            int mb = m0 + wm + i * 16 + quad * 4;
            int b = mb >> 10, s = mb & 1023;
            if (part == 2) {
                bf16x4 v4;
#pragma unroll
                for (int r = 0; r < 4; r++) v4[r] = (bf16)(acc[i][j][r] + bv);
                *(bf16x4*)&Vt[(size_t)((b * 16 + h) * 64 + dd) * 1024 + s] = v4;
            } else {
                float scv = (part == 0) ? 0.125f : 1.0f;
                bf16* dst = (part == 0 ? Qb : Kb) + (size_t)((b * 16 + h) * 1024 + s) * 64 + dd;
#pragma unroll
                for (int r = 0; r < 4; r++) dst[(size_t)r * 64] = (bf16)((acc[i][j][r] + bv) * scv);
            }
        }
    }
}

// ---------------- out-proj GEMM: 64x128 tile, 3-deep counted-vmcnt + T2 chunk swizzle ----------------
// 3 loads/stage -> steady wait vmcnt(6), tail 3/0. 3 bufs = 36KB LDS.
__global__ __launch_bounds__(256) void gemm_out_kernel(
    const bf16* __restrict__ A, const bf16* __restrict__ W,
    const float* __restrict__ bias, float* __restrict__ out)
{
    const int Kd = 1024;
    __shared__ bf16 sA[3][64 * 32];
    __shared__ bf16 sB[3][128 * 32];
    int tid = threadIdx.x, lane = tid & 63, wid = tid >> 6;
    int m0 = blockIdx.y * 64, n0 = blockIdx.x * 128;
    int ra = tid >> 2;                            // 0..63
    int pchunk = tid & 3;                         // physical chunk (LDS dest, linear)
    int jchunk = pchunk ^ ((tid >> 3) & 3);       // logical chunk (source); key=(ra>>1)&3
    const bf16* Ag = A + (size_t)(m0 + ra) * Kd + jchunk * 8;
    const bf16* Wg = W + (size_t)(n0 + ra) * Kd + jchunk * 8;
    int aoff = ra * 32 + pchunk * 8;
    int wm = (wid & 1) * 32, wn = (wid >> 1) * 64;
    int lcol = lane & 15, quad = lane >> 4;
    int ckey = (lcol >> 1) & 3;
    f32x4 acc[2][4] = {};
#define STG_O(buf, k0_) do { \
        async_load16(Ag + (k0_), &sA[buf][aoff]); \
        async_load16(Wg + (k0_), &sB[buf][aoff]); \
        async_load16(Wg + (k0_) + 64 * Kd, &sB[buf][aoff + 64 * 32]); \
    } while (0)
    STG_O(0, 0);
    STG_O(1, 32);
    STG_O(2, 64);
    int cur = 0;
    for (int it = 0; it < 32; ++it) {
        if (it < 30)      { WAITCNT_VM(6); }
        else if (it == 30){ WAITCNT_VM(3); }
        else              { WAITCNT_VM(0); }
        __builtin_amdgcn_s_barrier();
        CFENCE();
        const bf16* cA = sA[cur];
        const bf16* cB = sB[cur];
        bf16x8 af[2], bfr[4];
#pragma unroll
        for (int i = 0; i < 2; i++)
            af[i] = *(const bf16x8*)&cA[(wm + i * 16 + lcol) * 32 + (quad ^ ckey) * 8];
#pragma unroll
        for (int j = 0; j < 4; j++)
            bfr[j] = *(const bf16x8*)&cB[(wn + j * 16 + lcol) * 32 + (quad ^ ckey) * 8];
#pragma unroll
        for (int i = 0; i < 2; i++)
#pragma unroll
            for (int j = 0; j < 4; j++)
                acc[i][j] = MFMA_BF16(af[i], bfr[j], acc[i][j]);
        CFENCE();
        __builtin_amdgcn_s_barrier();
        if (it + 3 < 32) STG_O(cur, (it + 3) * 32);
        cur = (cur == 2) ? 0 : cur + 1;
    }
#undef STG_O
#pragma unroll
    for (int j = 0; j < 4; j++) {
        int n = n0 + wn + j * 16 + lcol;
        float bv = bias[n];
#pragma unroll
        for (int i = 0; i < 2; i++) {
            int m = m0 + wm + i * 16 + quad * 4;
#pragma unroll
            for (int r = 0; r < 4; r++) out[(size_t)(m + r) * 1024 + n] = acc[i][j][r] + bv;
        }
    }
}

// ---------------- flash attention: dbuf K/V + XOR bank swizzle + XCD-aware block swizzle ----------------
// T1: nwg=1024, 8 XCDs. orig = (id&7)*128 + id>>3 puts all 16 q-tiles of one (b,h)
// on ONE XCD -> K/V panels (128KB/head) become L2-resident instead of being
// re-fetched by all 8 XCDs.
__global__ __launch_bounds__(256) void flash_kernel(
    const bf16* __restrict__ Qb, const bf16* __restrict__ Kb, const bf16* __restrict__ Vt,
    bf16* __restrict__ ctx, float* __restrict__ ml)
{
    __shared__ bf16 sK[2][64 * 64];     // [buf][key][d], chunk-swizzled
    __shared__ bf16 sV[2][64 * 64];     // [buf][d][key], chunk-swizzled
    __shared__ bf16 pt[4][16 * 64];     // per-wave 16q x 64k transpose tile, XOR-swizzled
    int tid = threadIdx.x, lane = tid & 63, wid = tid >> 6;
    int bx = blockIdx.x;
    int orig = (bx & 7) * 128 + (bx >> 3);   // XCD-contiguous remap (bijective, 1024 % 8 == 0)
    int qt = orig & 15;
    int h = (orig >> 4) & 15;
    int b = orig >> 8;
    int lcol = lane & 15, quad = lane >> 4;
    size_t base = (size_t)(b * 16 + h) * 65536;

    int q0 = qt * 64 + wid * 16;
    const bf16* qp = Qb + base + (size_t)(q0 + lcol) * 64 + quad * 8;
    bf16x8 a0 = *(const bf16x8*)qp;
    bf16x8 a1 = *(const bf16x8*)(qp + 32);

    char* wpt = (char*)&pt[wid][0];
    int rr8 = lane >> 3;                 // 0..7 (row within 8-row staging group)
    int pp  = lane & 7;                  // physical chunk
    int jj  = pp ^ rr8;                  // logical chunk (swizzle key = row & 7 = rr8)
    int sr0 = wid * 16 + rr8;            // staged row (rows sr0, sr0+8; (+8)&7 preserved)
    int sw  = lcol & 7;                  // read-side swizzle key

#define STAGE_KV(buf, kt_) do { \
        async_load16(Kb + base + (size_t)((kt_) * 64 + sr0) * 64 + jj * 8,       &sK[buf][sr0 * 64 + pp * 8]); \
        async_load16(Kb + base + (size_t)((kt_) * 64 + sr0 + 8) * 64 + jj * 8,   &sK[buf][(sr0 + 8) * 64 + pp * 8]); \
        async_load16(Vt + base + (size_t)sr0 * 1024 + (kt_) * 64 + jj * 8,       &sV[buf][sr0 * 64 + pp * 8]); \
        async_load16(Vt + base + (size_t)(sr0 + 8) * 1024 + (kt_) * 64 + jj * 8, &sV[buf][(sr0 + 8) * 64 + pp * 8]); \
    } while (0)

    float l_[4] = {0.f, 0.f, 0.f, 0.f};
    f32x4 o[4] = {};

    STAGE_KV(0, 0);
    int cur = 0;
    for (int kt = 0; kt < 16; kt++) {
        __syncthreads();                 // buf[cur] ready; prior consumers of buf[cur^1] done
        if (kt < 15) STAGE_KV(cur ^ 1, kt + 1);
        const bf16* sKc = &sK[cur][0];
        const bf16* sVc = &sV[cur][0];
#pragma unroll
        for (int nt = 0; nt < 4; nt++) {
            int ck = quad ^ sw;
            bf16x8 bk0 = *(const bf16x8*)&sKc[(nt * 16 + lcol) * 64 + ck * 8];
            bf16x8 bk1 = *(const bf16x8*)&sKc[(nt * 16 + lcol) * 64 + (ck ^ 4) * 8];
            f32x4 s = {};
            s = MFMA_BF16(a0, bk0, s);
            s = MFMA_BF16(a1, bk1, s);
#pragma unroll
            for (int rr = 0; rr < 4; rr++) {
                float p = __expf(s[rr]);
                l_[rr] += p;
                int row = quad * 4 + rr;
                *(bf16*)(wpt + row * 128 + ((nt * 32 + lcol * 2) ^ ((row & 7) << 4))) = (bf16)p;
            }
        }
#pragma unroll
        for (int kf = 0; kf < 2; kf++) {
            bf16x8 pa = *(const bf16x8*)(wpt + lcol * 128 + (((kf * 4 + quad) ^ sw) << 4));
#pragma unroll
            for (int dt = 0; dt < 4; dt++) {
                bf16x8 vb = *(const bf16x8*)&sVc[(dt * 16 + lcol) * 64 + ((kf * 4 + quad) ^ sw) * 8];
                o[dt] = MFMA_BF16(pa, vb, o[dt]);
            }
        }
        cur ^= 1;
    }
#undef STAGE_KV
#pragma unroll
    for (int mk = 1; mk < 16; mk <<= 1)
#pragma unroll
        for (int rr = 0; rr < 4; rr++) l_[rr] += __shfl_xor(l_[rr], mk, 64);
#pragma unroll
    for (int rr = 0; rr < 4; rr++) {
        float inv = 1.f / l_[rr];
        int qg = q0 + quad * 4 + rr;
#pragma unroll
        for (int dt = 0; dt < 4; dt++)
            ctx[(size_t)(b * 1024 + qg) * 1024 + h * 64 + dt * 16 + lcol] = (bf16)(o[dt][rr] * inv);
        if (lcol == 0)
            ml[(size_t)(b * 16 + h) * 1024 + qg] = l_[rr];
    }
}

// ---------------- attn-weights: dbuf K staging + XOR swizzle + XCD-aware block swizzle ----------------
__global__ __launch_bounds__(256) void aw_kernel(
    const bf16* __restrict__ Qb, const bf16* __restrict__ Kb,
    const float* __restrict__ ml, float* __restrict__ aw)
{
    __shared__ bf16 sK[2][64 * 64];   // [buf][key][d], chunk-swizzled
    int tid = threadIdx.x, lane = tid & 63, wid = tid >> 6;
    int bx = blockIdx.x;
    int orig = (bx & 7) * 128 + (bx >> 3);
    int kt = orig & 15;
    int qt = (orig >> 4) & 15;
    int b = orig >> 8;
    int lcol = lane & 15, quad = lane >> 4;
    int q0 = qt * 64 + wid * 16;
    int kbase = kt * 64;
    int sw = lcol & 7;
    // staging geometry (two 16B chunks per thread)
    int r0_ = tid >> 3, p0_ = tid & 7, j0_ = p0_ ^ (r0_ & 7);
    int r1_ = (tid + 256) >> 3, p1_ = (tid + 256) & 7, j1_ = p1_ ^ (r1_ & 7);

#define STAGE_K(buf, hh) do { \
        size_t hb_ = (size_t)(b * 16 + (hh)) * 65536; \
        async_load16(Kb + hb_ + (size_t)(kbase + r0_) * 64 + j0_ * 8, &sK[buf][(size_t)tid * 8]); \
        async_load16(Kb + hb_ + (size_t)(kbase + r1_) * 64 + j1_ * 8, &sK[buf][(size_t)(tid + 256) * 8]); \
    } while (0)

    float acc[16];
#pragma unroll
    for (int i = 0; i < 16; i++) acc[i] = 0.f;

    STAGE_K(0, 0);
    int cur = 0;
    for (int h = 0; h < 16; h++) {
        size_t base = (size_t)(b * 16 + h) * 65536;
        const bf16* qp = Qb + base + (size_t)(q0 + lcol) * 64 + quad * 8;
        bf16x8 a0 = *(const bf16x8*)qp;
        bf16x8 a1 = *(const bf16x8*)(qp + 32);
        float scale[4];
#pragma unroll
        for (int rr = 0; rr < 4; rr++)
            scale[rr] = 0.0625f / ml[(size_t)(b * 16 + h) * 1024 + q0 + quad * 4 + rr];
        __syncthreads();                 // sK[cur] staged; prior consumers of sK[cur^1] done
        if (h < 15) STAGE_K(cur ^ 1, h + 1);
#pragma unroll
        for (int nt = 0; nt < 4; nt++) {
            int ck = quad ^ sw;
            bf16x8 bk0 = *(const bf16x8*)&sK[cur][(nt * 16 + lcol) * 64 + ck * 8];
            bf16x8 bk1 = *(const bf16x8*)&sK[cur][(nt * 16 + lcol) * 64 + (ck ^ 4) * 8];
            f32x4 s = {};
            s = MFMA_BF16(a0, bk0, s);
            s = MFMA_BF16(a1, bk1, s);
#pragma unroll
            for (int rr = 0; rr < 4; rr++)
                acc[nt * 4 + rr] += __expf(s[rr]) * scale[rr];
        }
        cur ^= 1;
    }
#undef STAGE_K
#pragma unroll
    for (int nt = 0; nt < 4; nt++)
#pragma unroll
        for (int rr = 0; rr < 4; rr++)
            aw[(size_t)(b * 1024 + q0 + quad * 4 + rr) * 1024 + kbase + nt * 16 + lcol] = acc[nt * 4 + rr];
}

// ---------------- residual + LayerNorm (fp32 output) ----------------
__global__ __launch_bounds__(256) void ln_kernel(
    const float* __restrict__ x, const float* __restrict__ ao,
    const float* __restrict__ w, const float* __restrict__ bsh,
    float* __restrict__ y)
{
    int row = blockIdx.x, tid = threadIdx.x;
    float4 xv = ((const float4*)(x + (size_t)row * 1024))[tid];
    float4 av = ((const float4*)(ao + (size_t)row * 1024))[tid];
    float4 v = {xv.x + av.x, xv.y + av.y, xv.z + av.z, xv.w + av.w};
    float s = v.x + v.y + v.z + v.w;
    float ss = v.x * v.x + v.y * v.y + v.z * v.z + v.w * v.w;
#pragma unroll
    for (int off = 32; off; off >>= 1) { s += __shfl_down(s, off); ss += __shfl_down(ss, off); }
    __shared__ float rs[4], rss[4];
    int lane = tid & 63, wid = tid >> 6;
    if (lane == 0) { rs[wid] = s; rss[wid] = ss; }
    __syncthreads();
    s = rs[0] + rs[1] + rs[2] + rs[3];
    ss = rss[0] + rss[1] + rss[2] + rss[3];
    float mean = s * (1.f / 1024.f);
    float var = ss * (1.f / 1024.f) - mean * mean;
    float inv = rsqrtf(var + 1e-5f);
    float4 wv = ((const float4*)w)[tid];
    float4 bv = ((const float4*)bsh)[tid];
    float4 o;
    o.x = (v.x - mean) * inv * wv.x + bv.x;
    o.y = (v.y - mean) * inv * wv.y + bv.y;
    o.z = (v.z - mean) * inv * wv.z + bv.z;
    o.w = (v.w - mean) * inv * wv.w + bv.w;
    ((float4*)y)[row * 256 + tid] = o;
}

extern "C" void kernel_launch(void* const* d_in, const int* in_sizes, int n_in,
                              void* d_out, int out_size, void* d_ws, size_t ws_size,
                              hipStream_t stream) {
    const float* x     = (const float*)d_in[0];
    const float* w_qkv = (const float*)d_in[1];
    const float* b_qkv = (const float*)d_in[2];
    const float* w_out = (const float*)d_in[3];
    const float* b_out = (const float*)d_in[4];
    const float* ln_w  = (const float*)d_in[5];
    const float* ln_b  = (const float*)d_in[6];

    char* ws = (char*)d_ws;
    // [0,8M) Qb | [8,16M) Kb | [16,24M) Vt | [24,32M) ctx | [32,32.25M) ml(l, fp32) |
    // x_bf [33,41M), wq_bf [41,47M) live only until gemm_qkv;
    // wo_bf [16,18M) after aw (Vt dead); ao fp32 [0,16M) after aw (Qb/Kb dead).
    bf16*   Qb    = (bf16*)(ws);
    bf16*   Kb    = (bf16*)(ws + (8ull  << 20));
    bf16*   Vt    = (bf16*)(ws + (16ull << 20));
    bf16*   ctx   = (bf16*)(ws + (24ull << 20));
    float*  ml    = (float*)(ws + (32ull << 20));
    bf16*   x_bf  = (bf16*)(ws + (33ull << 20));
    bf16*   wq_bf = (bf16*)(ws + (41ull << 20));
    bf16*   wo_bf = (bf16*)(ws + (16ull << 20));
    float*  ao    = (float*)(ws);

    float* y_out  = (float*)d_out;
    float* aw_out = y_out + 4ull * 1024 * 1024;

    cvt_kernel<<<4096, 256, 0, stream>>>(x, x_bf, 1048576);
    cvt_kernel<<<3072, 256, 0, stream>>>(w_qkv, wq_bf, 786432);
    gemm_qkv_kernel<<<dim3(24, 32), 256, 0, stream>>>(x_bf, wq_bf, b_qkv, Qb, Kb, Vt);
    flash_kernel<<<1024, 256, 0, stream>>>(Qb, Kb, Vt, ctx, ml);
    aw_kernel<<<1024, 256, 0, stream>>>(Qb, Kb, ml, aw_out);
    cvt_kernel<<<1024, 256, 0, stream>>>(w_out, wo_bf, 262144);
    gemm_out_kernel<<<dim3(8, 64), 256, 0, stream>>>(ctx, wo_bf, b_out, ao);
    ln_kernel<<<4096, 256, 0, stream>>>(x, ao, ln_w, ln_b, y_out);
}

// Round 5
// 208.933 us; speedup vs baseline: 1.0597x; 1.0439x over previous
//
#include <hip/hip_runtime.h>
#include <cstdint>

typedef __bf16 bf16;
typedef __bf16 bf16x8 __attribute__((ext_vector_type(8)));
typedef __bf16 bf16x4 __attribute__((ext_vector_type(4)));
typedef float  f32x4  __attribute__((ext_vector_type(4)));

#define MFMA_BF16(a, b, c) __builtin_amdgcn_mfma_f32_16x16x32_bf16(a, b, c, 0, 0, 0)

// counted vmcnt wait (T4): leave N loads in flight; "memory" clobber fences
// compiler-managed LDS reads from moving above it.
#define WAITCNT_VM(n) asm volatile("s_waitcnt vmcnt(" #n ")" ::: "memory")
#define CFENCE()      asm volatile("" ::: "memory")

// async global->LDS, 16B/lane; LDS dest affine in lane (base + lane*16).
__device__ __forceinline__ void async_load16(const void* g, void* l) {
    __builtin_amdgcn_global_load_lds(
        (__attribute__((address_space(1))) uint32_t*)(uintptr_t)g,
        (__attribute__((address_space(3))) uint32_t*)(uint32_t)(uintptr_t)l,
        16, 0, 0);
}

// ---------------- fp32 -> bf16 convert ----------------
__global__ void cvt_kernel(const float* __restrict__ src, bf16* __restrict__ dst, int n4) {
    int i = blockIdx.x * blockDim.x + threadIdx.x;
    if (i < n4) {
        float4 v = ((const float4*)src)[i];
        bf16x4 o;
        o[0] = (bf16)v.x; o[1] = (bf16)v.y; o[2] = (bf16)v.z; o[3] = (bf16)v.w;
        ((bf16x4*)dst)[i] = o;
    }
}

// ---------------- QKV GEMM: 3-deep counted-vmcnt pipeline + T2 swizzle + T1 XCD remap ----------------
__global__ __launch_bounds__(256) void gemm_qkv_kernel(
    const bf16* __restrict__ A, const bf16* __restrict__ W,
    const float* __restrict__ bias,
    bf16* __restrict__ Qb, bf16* __restrict__ Kb, bf16* __restrict__ Vt)
{
    const int Kd = 1024;
    __shared__ bf16 sA[3][128 * 32];
    __shared__ bf16 sB[3][128 * 32];
    int tid = threadIdx.x, lane = tid & 63, wid = tid >> 6;
    int flat = blockIdx.y * 24 + blockIdx.x;          // 0..767
    int orig = (flat & 7) * 96 + (flat >> 3);         // XCD-contiguous (768 % 8 == 0)
    int m0 = (orig / 24) * 128, n0 = (orig % 24) * 128;
    int srow = wid * 32 + (lane >> 2);
    int pchunk = lane & 3;                       // physical chunk (LDS dest, linear)
    int jchunk = pchunk ^ ((lane >> 3) & 3);     // logical chunk (source); key=(srow>>1)&3
    const bf16* Ag = A + (size_t)(m0 + srow) * Kd + jchunk * 8;
    const bf16* Wg = W + (size_t)(n0 + srow) * Kd + jchunk * 8;
    int soff = srow * 32 + pchunk * 8;
    int wm = (wid & 1) * 64, wn = (wid >> 1) * 64;
    int lcol = lane & 15, quad = lane >> 4;
    int ckey = (lcol >> 1) & 3;                  // read-side swizzle key
    f32x4 acc[4][4] = {};
#define STG_Q(buf, k0_) do { \
        async_load16(Ag + (k0_), &sA[buf][soff]); \
        async_load16(Ag + (k0_) + 16 * Kd, &sA[buf][soff + 512]); \
        async_load16(Wg + (k0_), &sB[buf][soff]); \
        async_load16(Wg + (k0_) + 16 * Kd, &sB[buf][soff + 512]); \
    } while (0)
    STG_Q(0, 0);
    STG_Q(1, 32);
    STG_Q(2, 64);
    int cur = 0;
    for (int it = 0; it < 32; ++it) {
        if (it < 30)      { WAITCNT_VM(8); }   // tiles it+1, it+2 stay in flight
        else if (it == 30){ WAITCNT_VM(4); }
        else              { WAITCNT_VM(0); }
        __builtin_amdgcn_s_barrier();   // buf[cur] staged by ALL waves
        CFENCE();
        const bf16* cA = sA[cur];
        const bf16* cB = sB[cur];
        bf16x8 af[4], bfr[4];
#pragma unroll
        for (int i = 0; i < 4; i++)
            af[i] = *(const bf16x8*)&cA[(wm + i * 16 + lcol) * 32 + (quad ^ ckey) * 8];
#pragma unroll
        for (int i = 0; i < 4; i++)
            bfr[i] = *(const bf16x8*)&cB[(wn + i * 16 + lcol) * 32 + (quad ^ ckey) * 8];
#pragma unroll
        for (int i = 0; i < 4; i++)
#pragma unroll
            for (int j = 0; j < 4; j++)
                acc[i][j] = MFMA_BF16(af[i], bfr[j], acc[i][j]);
        CFENCE();
        __builtin_amdgcn_s_barrier();   // all waves done reading buf[cur]
        if (it + 3 < 32) STG_Q(cur, (it + 3) * 32);   // refill the buffer just consumed
        cur = (cur == 2) ? 0 : cur + 1;
    }
#undef STG_Q
#pragma unroll
    for (int j = 0; j < 4; j++) {
        int n = n0 + wn + j * 16 + lcol;
        float bv = bias[n];
        int part = n >> 10, d = n & 1023, h = d >> 6, dd = d & 63;
#pragma unroll
        for (int i = 0; i < 4; i++) {
            int mb = m0 + wm + i * 16 + quad * 4;
            int b = mb >> 10, s = mb & 1023;
            if (part == 2) {
                bf16x4 v4;
#pragma unroll
                for (int r = 0; r < 4; r++) v4[r] = (bf16)(acc[i][j][r] + bv);
                *(bf16x4*)&Vt[(size_t)((b * 16 + h) * 64 + dd) * 1024 + s] = v4;
            } else {
                float scv = (part == 0) ? 0.125f : 1.0f;
                bf16* dst = (part == 0 ? Qb : Kb) + (size_t)((b * 16 + h) * 1024 + s) * 64 + dd;
#pragma unroll
                for (int r = 0; r < 4; r++) dst[(size_t)r * 64] = (bf16)((acc[i][j][r] + bv) * scv);
            }
        }
    }
}

// ---------------- out-proj GEMM: 64x128 tile, 3-deep counted-vmcnt + T2 chunk swizzle ----------------
__global__ __launch_bounds__(256) void gemm_out_kernel(
    const bf16* __restrict__ A, const bf16* __restrict__ W,
    const float* __restrict__ bias, float* __restrict__ out)
{
    const int Kd = 1024;
    __shared__ bf16 sA[3][64 * 32];
    __shared__ bf16 sB[3][128 * 32];
    int tid = threadIdx.x, lane = tid & 63, wid = tid >> 6;
    int m0 = blockIdx.y * 64, n0 = blockIdx.x * 128;
    int ra = tid >> 2;                            // 0..63
    int pchunk = tid & 3;                         // physical chunk (LDS dest, linear)
    int jchunk = pchunk ^ ((tid >> 3) & 3);       // logical chunk (source); key=(ra>>1)&3
    const bf16* Ag = A + (size_t)(m0 + ra) * Kd + jchunk * 8;
    const bf16* Wg = W + (size_t)(n0 + ra) * Kd + jchunk * 8;
    int aoff = ra * 32 + pchunk * 8;
    int wm = (wid & 1) * 32, wn = (wid >> 1) * 64;
    int lcol = lane & 15, quad = lane >> 4;
    int ckey = (lcol >> 1) & 3;
    f32x4 acc[2][4] = {};
#define STG_O(buf, k0_) do { \
        async_load16(Ag + (k0_), &sA[buf][aoff]); \
        async_load16(Wg + (k0_), &sB[buf][aoff]); \
        async_load16(Wg + (k0_) + 64 * Kd, &sB[buf][aoff + 64 * 32]); \
    } while (0)
    STG_O(0, 0);
    STG_O(1, 32);
    STG_O(2, 64);
    int cur = 0;
    for (int it = 0; it < 32; ++it) {
        if (it < 30)      { WAITCNT_VM(6); }
        else if (it == 30){ WAITCNT_VM(3); }
        else              { WAITCNT_VM(0); }
        __builtin_amdgcn_s_barrier();
        CFENCE();
        const bf16* cA = sA[cur];
        const bf16* cB = sB[cur];
        bf16x8 af[2], bfr[4];
#pragma unroll
        for (int i = 0; i < 2; i++)
            af[i] = *(const bf16x8*)&cA[(wm + i * 16 + lcol) * 32 + (quad ^ ckey) * 8];
#pragma unroll
        for (int j = 0; j < 4; j++)
            bfr[j] = *(const bf16x8*)&cB[(wn + j * 16 + lcol) * 32 + (quad ^ ckey) * 8];
#pragma unroll
        for (int i = 0; i < 2; i++)
#pragma unroll
            for (int j = 0; j < 4; j++)
                acc[i][j] = MFMA_BF16(af[i], bfr[j], acc[i][j]);
        CFENCE();
        __builtin_amdgcn_s_barrier();
        if (it + 3 < 32) STG_O(cur, (it + 3) * 32);
        cur = (cur == 2) ? 0 : cur + 1;
    }
#undef STG_O
#pragma unroll
    for (int j = 0; j < 4; j++) {
        int n = n0 + wn + j * 16 + lcol;
        float bv = bias[n];
#pragma unroll
        for (int i = 0; i < 2; i++) {
            int m = m0 + wm + i * 16 + quad * 4;
#pragma unroll
            for (int r = 0; r < 4; r++) out[(size_t)(m + r) * 1024 + n] = acc[i][j][r] + bv;
        }
    }
}

// ---------------- flash attention: 8-wave blocks (128q), dbuf K/V + XOR swizzle + XCD remap ----------------
// R4 restructure: 512 blocks x 512 threads. Staging = 1 K-chunk + 1 V-chunk per thread
// (was 4/thread), LDS 48KB -> 3 blocks/CU = 24 waves/CU (was 16). Latency-bound kernel:
// TLP up, staging issue cost halved. XCD remap bijective (512%8==0): one XCD owns 8
// full heads' K/V (2MB < 4MB L2).
__global__ __launch_bounds__(512) void flash_kernel(
    const bf16* __restrict__ Qb, const bf16* __restrict__ Kb, const bf16* __restrict__ Vt,
    bf16* __restrict__ ctx, float* __restrict__ ml)
{
    __shared__ bf16 sK[2][64 * 64];     // [buf][key][d], chunk-swizzled
    __shared__ bf16 sV[2][64 * 64];     // [buf][d][key], chunk-swizzled
    __shared__ bf16 pt[8][16 * 64];     // per-wave 16q x 64k transpose tile, XOR-swizzled
    int tid = threadIdx.x, lane = tid & 63, wid = tid >> 6;
    int bx = blockIdx.x;
    int orig = (bx & 7) * 64 + (bx >> 3);   // XCD-contiguous remap (bijective, 512 % 8 == 0)
    int qt = orig & 7;
    int h = (orig >> 3) & 15;
    int b = orig >> 7;
    int lcol = lane & 15, quad = lane >> 4;
    size_t base = (size_t)(b * 16 + h) * 65536;

    int q0 = qt * 128 + wid * 16;
    const bf16* qp = Qb + base + (size_t)(q0 + lcol) * 64 + quad * 8;
    bf16x8 a0 = *(const bf16x8*)qp;
    bf16x8 a1 = *(const bf16x8*)(qp + 32);

    char* wpt = (char*)&pt[wid][0];
    int sr = tid >> 3;                   // staged row 0..63
    int pp = tid & 7;                    // physical chunk
    int jj = pp ^ (sr & 7);              // logical chunk (swizzle key = row & 7)
    int sw = lcol & 7;                   // read-side swizzle key

#define STAGE_KV(buf, kt_) do { \
        async_load16(Kb + base + (size_t)((kt_) * 64 + sr) * 64 + jj * 8, &sK[buf][sr * 64 + pp * 8]); \
        async_load16(Vt + base + (size_t)sr * 1024 + (kt_) * 64 + jj * 8, &sV[buf][sr * 64 + pp * 8]); \
    } while (0)

    float l_[4] = {0.f, 0.f, 0.f, 0.f};
    f32x4 o[4] = {};

    STAGE_KV(0, 0);
    int cur = 0;
    for (int kt = 0; kt < 16; kt++) {
        __syncthreads();                 // buf[cur] ready; prior consumers of buf[cur^1] done
        if (kt < 15) STAGE_KV(cur ^ 1, kt + 1);
        const bf16* sKc = &sK[cur][0];
        const bf16* sVc = &sV[cur][0];
#pragma unroll
        for (int nt = 0; nt < 4; nt++) {
            int ck = quad ^ sw;
            bf16x8 bk0 = *(const bf16x8*)&sKc[(nt * 16 + lcol) * 64 + ck * 8];
            bf16x8 bk1 = *(const bf16x8*)&sKc[(nt * 16 + lcol) * 64 + (ck ^ 4) * 8];
            f32x4 s = {};
            s = MFMA_BF16(a0, bk0, s);
            s = MFMA_BF16(a1, bk1, s);
#pragma unroll
            for (int rr = 0; rr < 4; rr++) {
                float p = __expf(s[rr]);
                l_[rr] += p;
                int row = quad * 4 + rr;
                *(bf16*)(wpt + row * 128 + ((nt * 32 + lcol * 2) ^ ((row & 7) << 4))) = (bf16)p;
            }
        }
#pragma unroll
        for (int kf = 0; kf < 2; kf++) {
            bf16x8 pa = *(const bf16x8*)(wpt + lcol * 128 + (((kf * 4 + quad) ^ sw) << 4));
#pragma unroll
            for (int dt = 0; dt < 4; dt++) {
                bf16x8 vb = *(const bf16x8*)&sVc[(dt * 16 + lcol) * 64 + ((kf * 4 + quad) ^ sw) * 8];
                o[dt] = MFMA_BF16(pa, vb, o[dt]);
            }
        }
        cur ^= 1;
    }
#undef STAGE_KV
#pragma unroll
    for (int mk = 1; mk < 16; mk <<= 1)
#pragma unroll
        for (int rr = 0; rr < 4; rr++) l_[rr] += __shfl_xor(l_[rr], mk, 64);
#pragma unroll
    for (int rr = 0; rr < 4; rr++) {
        float inv = 1.f / l_[rr];
        int qg = q0 + quad * 4 + rr;
#pragma unroll
        for (int dt = 0; dt < 4; dt++)
            ctx[(size_t)(b * 1024 + qg) * 1024 + h * 64 + dt * 16 + lcol] = (bf16)(o[dt][rr] * inv);
        if (lcol == 0)
            ml[(size_t)(b * 16 + h) * 1024 + qg] = l_[rr];
    }
}

// ---------------- attn-weights: 8-wave blocks (128q x 64k), reg-pipelined Q/ml + XCD remap ----------------
// R4 fix: Q/ml loads for head h+1 are issued AFTER the barrier (during head h's
// compute) so the barrier's vmcnt(0) drain hides them under compute — previously they
// were issued right BEFORE the barrier, which ate the full load latency cold, 16x.
__global__ __launch_bounds__(512) void aw_kernel(
    const bf16* __restrict__ Qb, const bf16* __restrict__ Kb,
    const float* __restrict__ ml, float* __restrict__ aw)
{
    __shared__ bf16 sK[2][64 * 64];   // [buf][key][d], chunk-swizzled
    int tid = threadIdx.x, lane = tid & 63, wid = tid >> 6;
    int bx = blockIdx.x;
    int orig = (bx & 7) * 64 + (bx >> 3);   // bijective (512 % 8 == 0)
    int kt = orig & 15;
    int qt = (orig >> 4) & 7;
    int b = orig >> 7;
    int lcol = lane & 15, quad = lane >> 4;
    int q0 = qt * 128 + wid * 16;
    int kbase = kt * 64;
    int sw = lcol & 7;
    int sr = tid >> 3, pp = tid & 7, jj = pp ^ (sr & 7);   // 1 chunk per thread (8KB)

#define STAGE_K(buf, hh) \
        async_load16(Kb + (size_t)(b * 16 + (hh)) * 65536 + (size_t)(kbase + sr) * 64 + jj * 8, \
                     &sK[buf][sr * 64 + pp * 8])

    float acc[16];
#pragma unroll
    for (int i = 0; i < 16; i++) acc[i] = 0.f;

    bf16x8 a0c, a1c, a0n, a1n;
    float4 mvC, mvN;
    {
        const bf16* qp = Qb + (size_t)(b * 16) * 65536 + (size_t)(q0 + lcol) * 64 + quad * 8;
        a0c = *(const bf16x8*)qp;
        a1c = *(const bf16x8*)(qp + 32);
        mvC = *(const float4*)(ml + (size_t)(b * 16) * 1024 + q0 + quad * 4);
    }
    STAGE_K(0, 0);
    int cur = 0;
    for (int h = 0; h < 16; h++) {
        __syncthreads();                 // sK[cur] staged; prior consumers of sK[cur^1] done
        if (h < 15) {
            STAGE_K(cur ^ 1, h + 1);
            const bf16* qp = Qb + (size_t)(b * 16 + h + 1) * 65536 + (size_t)(q0 + lcol) * 64 + quad * 8;
            a0n = *(const bf16x8*)qp;
            a1n = *(const bf16x8*)(qp + 32);
            mvN = *(const float4*)(ml + (size_t)(b * 16 + h + 1) * 1024 + q0 + quad * 4);
        }
        float scale[4] = {0.0625f / mvC.x, 0.0625f / mvC.y, 0.0625f / mvC.z, 0.0625f / mvC.w};
#pragma unroll
        for (int nt = 0; nt < 4; nt++) {
            int ck = quad ^ sw;
            bf16x8 bk0 = *(const bf16x8*)&sK[cur][(nt * 16 + lcol) * 64 + ck * 8];
            bf16x8 bk1 = *(const bf16x8*)&sK[cur][(nt * 16 + lcol) * 64 + (ck ^ 4) * 8];
            f32x4 s = {};
            s = MFMA_BF16(a0c, bk0, s);
            s = MFMA_BF16(a1c, bk1, s);
#pragma unroll
            for (int rr = 0; rr < 4; rr++)
                acc[nt * 4 + rr] += __expf(s[rr]) * scale[rr];
        }
        if (h < 15) { a0c = a0n; a1c = a1n; mvC = mvN; }
        cur ^= 1;
    }
#undef STAGE_K
#pragma unroll
    for (int nt = 0; nt < 4; nt++)
#pragma unroll
        for (int rr = 0; rr < 4; rr++)
            aw[(size_t)(b * 1024 + q0 + quad * 4 + rr) * 1024 + kbase + nt * 16 + lcol] = acc[nt * 4 + rr];
}

// ---------------- residual + LayerNorm (fp32 output) ----------------
__global__ __launch_bounds__(256) void ln_kernel(
    const float* __restrict__ x, const float* __restrict__ ao,
    const float* __restrict__ w, const float* __restrict__ bsh,
    float* __restrict__ y)
{
    int row = blockIdx.x, tid = threadIdx.x;
    float4 xv = ((const float4*)(x + (size_t)row * 1024))[tid];
    float4 av = ((const float4*)(ao + (size_t)row * 1024))[tid];
    float4 v = {xv.x + av.x, xv.y + av.y, xv.z + av.z, xv.w + av.w};
    float s = v.x + v.y + v.z + v.w;
    float ss = v.x * v.x + v.y * v.y + v.z * v.z + v.w * v.w;
#pragma unroll
    for (int off = 32; off; off >>= 1) { s += __shfl_down(s, off); ss += __shfl_down(ss, off); }
    __shared__ float rs[4], rss[4];
    int lane = tid & 63, wid = tid >> 6;
    if (lane == 0) { rs[wid] = s; rss[wid] = ss; }
    __syncthreads();
    s = rs[0] + rs[1] + rs[2] + rs[3];
    ss = rss[0] + rss[1] + rss[2] + rss[3];
    float mean = s * (1.f / 1024.f);
    float var = ss * (1.f / 1024.f) - mean * mean;
    float inv = rsqrtf(var + 1e-5f);
    float4 wv = ((const float4*)w)[tid];
    float4 bv = ((const float4*)bsh)[tid];
    float4 o;
    o.x = (v.x - mean) * inv * wv.x + bv.x;
    o.y = (v.y - mean) * inv * wv.y + bv.y;
    o.z = (v.z - mean) * inv * wv.z + bv.z;
    o.w = (v.w - mean) * inv * wv.w + bv.w;
    ((float4*)y)[row * 256 + tid] = o;
}

extern "C" void kernel_launch(void* const* d_in, const int* in_sizes, int n_in,
                              void* d_out, int out_size, void* d_ws, size_t ws_size,
                              hipStream_t stream) {
    const float* x     = (const float*)d_in[0];
    const float* w_qkv = (const float*)d_in[1];
    const float* b_qkv = (const float*)d_in[2];
    const float* w_out = (const float*)d_in[3];
    const float* b_out = (const float*)d_in[4];
    const float* ln_w  = (const float*)d_in[5];
    const float* ln_b  = (const float*)d_in[6];

    char* ws = (char*)d_ws;
    // [0,8M) Qb | [8,16M) Kb | [16,24M) Vt | [24,32M) ctx | [32,32.25M) ml(l, fp32) |
    // x_bf [33,41M), wq_bf [41,47M) live only until gemm_qkv;
    // wo_bf [16,18M) after aw (Vt dead); ao fp32 [0,16M) after aw (Qb/Kb dead).
    bf16*   Qb    = (bf16*)(ws);
    bf16*   Kb    = (bf16*)(ws + (8ull  << 20));
    bf16*   Vt    = (bf16*)(ws + (16ull << 20));
    bf16*   ctx   = (bf16*)(ws + (24ull << 20));
    float*  ml    = (float*)(ws + (32ull << 20));
    bf16*   x_bf  = (bf16*)(ws + (33ull << 20));
    bf16*   wq_bf = (bf16*)(ws + (41ull << 20));
    bf16*   wo_bf = (bf16*)(ws + (16ull << 20));
    float*  ao    = (float*)(ws);

    float* y_out  = (float*)d_out;
    float* aw_out = y_out + 4ull * 1024 * 1024;

    cvt_kernel<<<4096, 256, 0, stream>>>(x, x_bf, 1048576);
    cvt_kernel<<<3072, 256, 0, stream>>>(w_qkv, wq_bf, 786432);
    gemm_qkv_kernel<<<dim3(24, 32), 256, 0, stream>>>(x_bf, wq_bf, b_qkv, Qb, Kb, Vt);
    flash_kernel<<<512, 512, 0, stream>>>(Qb, Kb, Vt, ctx, ml);
    aw_kernel<<<512, 512, 0, stream>>>(Qb, Kb, ml, aw_out);
    cvt_kernel<<<1024, 256, 0, stream>>>(w_out, wo_bf, 262144);
    gemm_out_kernel<<<dim3(8, 64), 256, 0, stream>>>(ctx, wo_bf, b_out, ao);
    ln_kernel<<<4096, 256, 0, stream>>>(x, ao, ln_w, ln_b, y_out);
}

// Round 6
// 201.226 us; speedup vs baseline: 1.1002x; 1.0383x over previous
//
#include <hip/hip_runtime.h>
#include <cstdint>

typedef __bf16 bf16;
typedef __bf16 bf16x8 __attribute__((ext_vector_type(8)));
typedef __bf16 bf16x4 __attribute__((ext_vector_type(4)));
typedef float  f32x4  __attribute__((ext_vector_type(4)));

#define MFMA_BF16(a, b, c) __builtin_amdgcn_mfma_f32_16x16x32_bf16(a, b, c, 0, 0, 0)

#define WAITCNT_VM(n) asm volatile("s_waitcnt vmcnt(" #n ")" ::: "memory")
#define CFENCE()      asm volatile("" ::: "memory")

// async global->LDS, 16B/lane; LDS dest affine in lane (base + lane*16).
__device__ __forceinline__ void async_load16(const void* g, void* l) {
    __builtin_amdgcn_global_load_lds(
        (__attribute__((address_space(1))) uint32_t*)(uintptr_t)g,
        (__attribute__((address_space(3))) uint32_t*)(uint32_t)(uintptr_t)l,
        16, 0, 0);
}

// ---------------- fused fp32 -> bf16 convert (x + w_qkv in one launch) ----------------
__global__ void cvt3_kernel(const float* __restrict__ s0, bf16* __restrict__ d0, int n0,
                            const float* __restrict__ s1, bf16* __restrict__ d1, int n1) {
    int i = blockIdx.x * blockDim.x + threadIdx.x;
    const float* s; bf16* d; int j = i;
    if (j < n0) { s = s0; d = d0; }
    else { j -= n0; if (j >= n1) return; s = s1; d = d1; }
    float4 v = ((const float4*)s)[j];
    bf16x4 o;
    o[0] = (bf16)v.x; o[1] = (bf16)v.y; o[2] = (bf16)v.z; o[3] = (bf16)v.w;
    ((bf16x4*)d)[j] = o;
}

// ---------------- QKV GEMM: 3-deep counted-vmcnt pipeline + T2 swizzle + T1 XCD remap ----------------
// R6: coalesced epilogue. The old epilogue scatter-stored 2B/8B at strides 64/2048 ->
// write-allocate fetched ~24MB (FETCH 36MB vs 14MB compulsory) + 256 store instrs/block.
// Now: restage the 128x128 tile in LDS (padded stride 136 -> conflict-free), then 8
// fully-contiguous 16B stores/thread. Layout [m][n] for Q/K (contig in dd), [n][m] for Vt.
__global__ __launch_bounds__(256) void gemm_qkv_kernel(
    const bf16* __restrict__ A, const bf16* __restrict__ W,
    const float* __restrict__ bias,
    bf16* __restrict__ Qb, bf16* __restrict__ Kb, bf16* __restrict__ Vt)
{
    const int Kd = 1024;
    __shared__ __attribute__((aligned(16))) bf16 smem[6 * 128 * 32];   // 48KB: sA[3] | sB[3]
    bf16* const sA0 = smem;
    bf16* const sB0 = smem + 3 * 4096;
    int tid = threadIdx.x, lane = tid & 63, wid = tid >> 6;
    int flat = blockIdx.y * 24 + blockIdx.x;          // 0..767
    int orig = (flat & 7) * 96 + (flat >> 3);         // XCD-contiguous (768 % 8 == 0)
    int m0 = (orig / 24) * 128, n0 = (orig % 24) * 128;
    int srow = wid * 32 + (lane >> 2);
    int pchunk = lane & 3;                       // physical chunk (LDS dest, linear)
    int jchunk = pchunk ^ ((lane >> 3) & 3);     // logical chunk (source); key=(srow>>1)&3
    const bf16* Ag = A + (size_t)(m0 + srow) * Kd + jchunk * 8;
    const bf16* Wg = W + (size_t)(n0 + srow) * Kd + jchunk * 8;
    int soff = srow * 32 + pchunk * 8;
    int wm = (wid & 1) * 64, wn = (wid >> 1) * 64;
    int lcol = lane & 15, quad = lane >> 4;
    int ckey = (lcol >> 1) & 3;                  // read-side swizzle key
    f32x4 acc[4][4] = {};
#define STG_Q(buf, k0_) do { \
        async_load16(Ag + (k0_), sA0 + (buf) * 4096 + soff); \
        async_load16(Ag + (k0_) + 16 * Kd, sA0 + (buf) * 4096 + soff + 512); \
        async_load16(Wg + (k0_), sB0 + (buf) * 4096 + soff); \
        async_load16(Wg + (k0_) + 16 * Kd, sB0 + (buf) * 4096 + soff + 512); \
    } while (0)
    STG_Q(0, 0);
    STG_Q(1, 32);
    STG_Q(2, 64);
    int cur = 0;
    for (int it = 0; it < 32; ++it) {
        if (it < 30)      { WAITCNT_VM(8); }
        else if (it == 30){ WAITCNT_VM(4); }
        else              { WAITCNT_VM(0); }
        __builtin_amdgcn_s_barrier();
        CFENCE();
        const bf16* cA = sA0 + cur * 4096;
        const bf16* cB = sB0 + cur * 4096;
        bf16x8 af[4], bfr[4];
#pragma unroll
        for (int i = 0; i < 4; i++)
            af[i] = *(const bf16x8*)&cA[(wm + i * 16 + lcol) * 32 + (quad ^ ckey) * 8];
#pragma unroll
        for (int i = 0; i < 4; i++)
            bfr[i] = *(const bf16x8*)&cB[(wn + i * 16 + lcol) * 32 + (quad ^ ckey) * 8];
#pragma unroll
        for (int i = 0; i < 4; i++)
#pragma unroll
            for (int j = 0; j < 4; j++)
                acc[i][j] = MFMA_BF16(af[i], bfr[j], acc[i][j]);
        CFENCE();
        __builtin_amdgcn_s_barrier();
        if (it + 3 < 32) STG_Q(cur, (it + 3) * 32);
        cur = (cur == 2) ? 0 : cur + 1;
    }
#undef STG_Q
    // ---- coalesced epilogue (LDS restage) ----
    const int LP = 136;                    // padded bf16 row stride (272B)
    bf16* sE = smem;                       // 128*136*2B = 34KB <= 48KB
    int part = n0 >> 10;                   // whole block is one of Q/K/V
    int h0 = (n0 & 1023) >> 6;
    int b = m0 >> 10, s0 = m0 & 1023;
    if (part == 2) {
#pragma unroll
        for (int j = 0; j < 4; j++) {
            float bv = bias[n0 + wn + j * 16 + lcol];
#pragma unroll
            for (int i = 0; i < 4; i++)
#pragma unroll
                for (int r = 0; r < 4; r++)
                    sE[(wn + j * 16 + lcol) * LP + (wm + i * 16 + quad * 4 + r)] = (bf16)(acc[i][j][r] + bv);
        }
        __syncthreads();
#pragma unroll
        for (int p = 0; p < 8; p++) {
            int c = p * 256 + tid;
            int nl = c >> 4, mc = (c & 15) * 8;
            int dd = nl & 63, h = h0 + (nl >> 6);
            *(bf16x8*)&Vt[(size_t)((b * 16 + h) * 64 + dd) * 1024 + s0 + mc] = *(const bf16x8*)&sE[nl * LP + mc];
        }
    } else {
        float scv = (part == 0) ? 0.125f : 1.0f;
        bf16* dst = (part == 0) ? Qb : Kb;
#pragma unroll
        for (int j = 0; j < 4; j++) {
            float bv = bias[n0 + wn + j * 16 + lcol];
#pragma unroll
            for (int i = 0; i < 4; i++)
#pragma unroll
                for (int r = 0; r < 4; r++)
                    sE[(wm + i * 16 + quad * 4 + r) * LP + (wn + j * 16 + lcol)] = (bf16)((acc[i][j][r] + bv) * scv);
        }
        __syncthreads();
#pragma unroll
        for (int p = 0; p < 8; p++) {
            int c = p * 256 + tid;
            int half = c >> 10, idx = c & 1023;
            int m = idx >> 3, nc = (idx & 7) * 8;
            *(bf16x8*)&dst[(size_t)((b * 16 + h0 + half) * 1024 + s0 + m) * 64 + nc] =
                *(const bf16x8*)&sE[m * LP + half * 64 + nc];
        }
    }
}

// ---------------- out-proj GEMM: 64x128 tile, 3-deep counted-vmcnt + T2 chunk swizzle ----------------
__global__ __launch_bounds__(256) void gemm_out_kernel(
    const bf16* __restrict__ A, const bf16* __restrict__ W,
    const float* __restrict__ bias, float* __restrict__ out)
{
    const int Kd = 1024;
    __shared__ bf16 sA[3][64 * 32];
    __shared__ bf16 sB[3][128 * 32];
    int tid = threadIdx.x, lane = tid & 63, wid = tid >> 6;
    int m0 = blockIdx.y * 64, n0 = blockIdx.x * 128;
    int ra = tid >> 2;                            // 0..63
    int pchunk = tid & 3;
    int jchunk = pchunk ^ ((tid >> 3) & 3);
    const bf16* Ag = A + (size_t)(m0 + ra) * Kd + jchunk * 8;
    const bf16* Wg = W + (size_t)(n0 + ra) * Kd + jchunk * 8;
    int aoff = ra * 32 + pchunk * 8;
    int wm = (wid & 1) * 32, wn = (wid >> 1) * 64;
    int lcol = lane & 15, quad = lane >> 4;
    int ckey = (lcol >> 1) & 3;
    f32x4 acc[2][4] = {};
#define STG_O(buf, k0_) do { \
        async_load16(Ag + (k0_), &sA[buf][aoff]); \
        async_load16(Wg + (k0_), &sB[buf][aoff]); \
        async_load16(Wg + (k0_) + 64 * Kd, &sB[buf][aoff + 64 * 32]); \
    } while (0)
    STG_O(0, 0);
    STG_O(1, 32);
    STG_O(2, 64);
    int cur = 0;
    for (int it = 0; it < 32; ++it) {
        if (it < 30)      { WAITCNT_VM(6); }
        else if (it == 30){ WAITCNT_VM(3); }
        else              { WAITCNT_VM(0); }
        __builtin_amdgcn_s_barrier();
        CFENCE();
        const bf16* cA = sA[cur];
        const bf16* cB = sB[cur];
        bf16x8 af[2], bfr[4];
#pragma unroll
        for (int i = 0; i < 2; i++)
            af[i] = *(const bf16x8*)&cA[(wm + i * 16 + lcol) * 32 + (quad ^ ckey) * 8];
#pragma unroll
        for (int j = 0; j < 4; j++)
            bfr[j] = *(const bf16x8*)&cB[(wn + j * 16 + lcol) * 32 + (quad ^ ckey) * 8];
#pragma unroll
        for (int i = 0; i < 2; i++)
#pragma unroll
            for (int j = 0; j < 4; j++)
                acc[i][j] = MFMA_BF16(af[i], bfr[j], acc[i][j]);
        CFENCE();
        __builtin_amdgcn_s_barrier();
        if (it + 3 < 32) STG_O(cur, (it + 3) * 32);
        cur = (cur == 2) ? 0 : cur + 1;
    }
#undef STG_O
#pragma unroll
    for (int j = 0; j < 4; j++) {
        int n = n0 + wn + j * 16 + lcol;
        float bv = bias[n];
#pragma unroll
        for (int i = 0; i < 2; i++) {
            int m = m0 + wm + i * 16 + quad * 4;
#pragma unroll
            for (int r = 0; r < 4; r++) out[(size_t)(m + r) * 1024 + n] = acc[i][j][r] + bv;
        }
    }
}

// ---------------- flash attention: 8-wave blocks, dbuf K/V + XOR swizzle + XCD remap ----------------
// R6: ctx write coalesced — o staged through the wave-private pt tile (same XOR swizzle),
// then 2 x 1KB contiguous stores/wave (was 16 scalar 2B stores/wave -> write-allocate).
__global__ __launch_bounds__(512) void flash_kernel(
    const bf16* __restrict__ Qb, const bf16* __restrict__ Kb, const bf16* __restrict__ Vt,
    bf16* __restrict__ ctx, float* __restrict__ ml)
{
    __shared__ bf16 sK[2][64 * 64];     // [buf][key][d], chunk-swizzled
    __shared__ bf16 sV[2][64 * 64];     // [buf][d][key], chunk-swizzled
    __shared__ bf16 pt[8][16 * 64];     // per-wave 16q x 64k transpose tile, XOR-swizzled
    int tid = threadIdx.x, lane = tid & 63, wid = tid >> 6;
    int bx = blockIdx.x;
    int orig = (bx & 7) * 64 + (bx >> 3);   // XCD-contiguous remap (bijective, 512 % 8 == 0)
    int qt = orig & 7;
    int h = (orig >> 3) & 15;
    int b = orig >> 7;
    int lcol = lane & 15, quad = lane >> 4;
    size_t base = (size_t)(b * 16 + h) * 65536;

    int q0 = qt * 128 + wid * 16;
    const bf16* qp = Qb + base + (size_t)(q0 + lcol) * 64 + quad * 8;
    bf16x8 a0 = *(const bf16x8*)qp;
    bf16x8 a1 = *(const bf16x8*)(qp + 32);

    char* wpt = (char*)&pt[wid][0];
    int sr = tid >> 3;                   // staged row 0..63
    int pp = tid & 7;                    // physical chunk
    int jj = pp ^ (sr & 7);              // logical chunk (swizzle key = row & 7)
    int sw = lcol & 7;                   // read-side swizzle key

#define STAGE_KV(buf, kt_) do { \
        async_load16(Kb + base + (size_t)((kt_) * 64 + sr) * 64 + jj * 8, &sK[buf][sr * 64 + pp * 8]); \
        async_load16(Vt + base + (size_t)sr * 1024 + (kt_) * 64 + jj * 8, &sV[buf][sr * 64 + pp * 8]); \
    } while (0)

    float l_[4] = {0.f, 0.f, 0.f, 0.f};
    f32x4 o[4] = {};

    STAGE_KV(0, 0);
    int cur = 0;
    for (int kt = 0; kt < 16; kt++) {
        __syncthreads();
        if (kt < 15) STAGE_KV(cur ^ 1, kt + 1);
        const bf16* sKc = &sK[cur][0];
        const bf16* sVc = &sV[cur][0];
#pragma unroll
        for (int nt = 0; nt < 4; nt++) {
            int ck = quad ^ sw;
            bf16x8 bk0 = *(const bf16x8*)&sKc[(nt * 16 + lcol) * 64 + ck * 8];
            bf16x8 bk1 = *(const bf16x8*)&sKc[(nt * 16 + lcol) * 64 + (ck ^ 4) * 8];
            f32x4 s = {};
            s = MFMA_BF16(a0, bk0, s);
            s = MFMA_BF16(a1, bk1, s);
#pragma unroll
            for (int rr = 0; rr < 4; rr++) {
                float p = __expf(s[rr]);
                l_[rr] += p;
                int row = quad * 4 + rr;
                *(bf16*)(wpt + row * 128 + ((nt * 32 + lcol * 2) ^ ((row & 7) << 4))) = (bf16)p;
            }
        }
#pragma unroll
        for (int kf = 0; kf < 2; kf++) {
            bf16x8 pa = *(const bf16x8*)(wpt + lcol * 128 + (((kf * 4 + quad) ^ sw) << 4));
#pragma unroll
            for (int dt = 0; dt < 4; dt++) {
                bf16x8 vb = *(const bf16x8*)&sVc[(dt * 16 + lcol) * 64 + ((kf * 4 + quad) ^ sw) * 8];
                o[dt] = MFMA_BF16(pa, vb, o[dt]);
            }
        }
        cur ^= 1;
    }
#undef STAGE_KV
#pragma unroll
    for (int mk = 1; mk < 16; mk <<= 1)
#pragma unroll
        for (int rr = 0; rr < 4; rr++) l_[rr] += __shfl_xor(l_[rr], mk, 64);
    // stage o -> pt (wave-private, swizzled; same key as P-writes), then coalesced stores
#pragma unroll
    for (int rr = 0; rr < 4; rr++) {
        float inv = 1.f / l_[rr];
        int row = quad * 4 + rr;
#pragma unroll
        for (int dt = 0; dt < 4; dt++)
            *(bf16*)(wpt + row * 128 + ((dt * 32 + lcol * 2) ^ ((row & 7) << 4))) = (bf16)(o[dt][rr] * inv);
        if (lcol == 0)
            ml[(size_t)(b * 16 + h) * 1024 + q0 + row] = l_[rr];
    }
    int r8a = lane >> 3, ca = lane & 7;
#pragma unroll
    for (int half = 0; half < 2; half++) {
        int r8 = r8a + half * 8;
        bf16x8 v = *(const bf16x8*)(wpt + r8 * 128 + ((ca * 16) ^ ((r8 & 7) << 4)));
        *(bf16x8*)&ctx[(size_t)(b * 1024 + q0 + r8) * 1024 + h * 64 + ca * 8] = v;
    }
}

// ---------------- attn-weights (+ piggybacked w_out cvt): 8-wave blocks, reg-pipelined Q/ml ----------------
// Blocks 0..511: aw. Blocks 512..1023: w_out fp32->bf16 (runs after flash, when Vt region
// is dead) — saves a separate cvt launch.
__global__ __launch_bounds__(512) void aw_kernel(
    const bf16* __restrict__ Qb, const bf16* __restrict__ Kb,
    const float* __restrict__ ml, float* __restrict__ aw,
    const float* __restrict__ wof, bf16* __restrict__ wob)
{
    __shared__ bf16 sK[2][64 * 64];   // [buf][key][d], chunk-swizzled
    int tid = threadIdx.x, lane = tid & 63, wid = tid >> 6;
    int bx = blockIdx.x;
    if (bx >= 512) {
        int i = (bx - 512) * 512 + tid;          // [0, 262144)
        float4 v = ((const float4*)wof)[i];
        bf16x4 o;
        o[0] = (bf16)v.x; o[1] = (bf16)v.y; o[2] = (bf16)v.z; o[3] = (bf16)v.w;
        ((bf16x4*)wob)[i] = o;
        return;
    }
    int orig = (bx & 7) * 64 + (bx >> 3);   // bijective (512 % 8 == 0)
    int kt = orig & 15;
    int qt = (orig >> 4) & 7;
    int b = orig >> 7;
    int lcol = lane & 15, quad = lane >> 4;
    int q0 = qt * 128 + wid * 16;
    int kbase = kt * 64;
    int sw = lcol & 7;
    int sr = tid >> 3, pp = tid & 7, jj = pp ^ (sr & 7);   // 1 chunk per thread (8KB)

#define STAGE_K(buf, hh) \
        async_load16(Kb + (size_t)(b * 16 + (hh)) * 65536 + (size_t)(kbase + sr) * 64 + jj * 8, \
                     &sK[buf][sr * 64 + pp * 8])

    float acc[16];
#pragma unroll
    for (int i = 0; i < 16; i++) acc[i] = 0.f;

    bf16x8 a0c, a1c, a0n, a1n;
    float4 mvC, mvN;
    {
        const bf16* qp = Qb + (size_t)(b * 16) * 65536 + (size_t)(q0 + lcol) * 64 + quad * 8;
        a0c = *(const bf16x8*)qp;
        a1c = *(const bf16x8*)(qp + 32);
        mvC = *(const float4*)(ml + (size_t)(b * 16) * 1024 + q0 + quad * 4);
    }
    STAGE_K(0, 0);
    int cur = 0;
    for (int h = 0; h < 16; h++) {
        __syncthreads();
        if (h < 15) {
            STAGE_K(cur ^ 1, h + 1);
            const bf16* qp = Qb + (size_t)(b * 16 + h + 1) * 65536 + (size_t)(q0 + lcol) * 64 + quad * 8;
            a0n = *(const bf16x8*)qp;
            a1n = *(const bf16x8*)(qp + 32);
            mvN = *(const float4*)(ml + (size_t)(b * 16 + h + 1) * 1024 + q0 + quad * 4);
        }
        float scale[4] = {0.0625f / mvC.x, 0.0625f / mvC.y, 0.0625f / mvC.z, 0.0625f / mvC.w};
#pragma unroll
        for (int nt = 0; nt < 4; nt++) {
            int ck = quad ^ sw;
            bf16x8 bk0 = *(const bf16x8*)&sK[cur][(nt * 16 + lcol) * 64 + ck * 8];
            bf16x8 bk1 = *(const bf16x8*)&sK[cur][(nt * 16 + lcol) * 64 + (ck ^ 4) * 8];
            f32x4 s = {};
            s = MFMA_BF16(a0c, bk0, s);
            s = MFMA_BF16(a1c, bk1, s);
#pragma unroll
            for (int rr = 0; rr < 4; rr++)
                acc[nt * 4 + rr] += __expf(s[rr]) * scale[rr];
        }
        if (h < 15) { a0c = a0n; a1c = a1n; mvC = mvN; }
        cur ^= 1;
    }
#undef STAGE_K
#pragma unroll
    for (int nt = 0; nt < 4; nt++)
#pragma unroll
        for (int rr = 0; rr < 4; rr++)
            aw[(size_t)(b * 1024 + q0 + quad * 4 + rr) * 1024 + kbase + nt * 16 + lcol] = acc[nt * 4 + rr];
}

// ---------------- residual + LayerNorm (fp32 output) ----------------
__global__ __launch_bounds__(256) void ln_kernel(
    const float* __restrict__ x, const float* __restrict__ ao,
    const float* __restrict__ w, const float* __restrict__ bsh,
    float* __restrict__ y)
{
    int row = blockIdx.x, tid = threadIdx.x;
    float4 xv = ((const float4*)(x + (size_t)row * 1024))[tid];
    float4 av = ((const float4*)(ao + (size_t)row * 1024))[tid];
    float4 v = {xv.x + av.x, xv.y + av.y, xv.z + av.z, xv.w + av.w};
    float s = v.x + v.y + v.z + v.w;
    float ss = v.x * v.x + v.y * v.y + v.z * v.z + v.w * v.w;
#pragma unroll
    for (int off = 32; off; off >>= 1) { s += __shfl_down(s, off); ss += __shfl_down(ss, off); }
    __shared__ float rs[4], rss[4];
    int lane = tid & 63, wid = tid >> 6;
    if (lane == 0) { rs[wid] = s; rss[wid] = ss; }
    __syncthreads();
    s = rs[0] + rs[1] + rs[2] + rs[3];
    ss = rss[0] + rss[1] + rss[2] + rss[3];
    float mean = s * (1.f / 1024.f);
    float var = ss * (1.f / 1024.f) - mean * mean;
    float inv = rsqrtf(var + 1e-5f);
    float4 wv = ((const float4*)w)[tid];
    float4 bv = ((const float4*)bsh)[tid];
    float4 o;
    o.x = (v.x - mean) * inv * wv.x + bv.x;
    o.y = (v.y - mean) * inv * wv.y + bv.y;
    o.z = (v.z - mean) * inv * wv.z + bv.z;
    o.w = (v.w - mean) * inv * wv.w + bv.w;
    ((float4*)y)[row * 256 + tid] = o;
}

extern "C" void kernel_launch(void* const* d_in, const int* in_sizes, int n_in,
                              void* d_out, int out_size, void* d_ws, size_t ws_size,
                              hipStream_t stream) {
    const float* x     = (const float*)d_in[0];
    const float* w_qkv = (const float*)d_in[1];
    const float* b_qkv = (const float*)d_in[2];
    const float* w_out = (const float*)d_in[3];
    const float* b_out = (const float*)d_in[4];
    const float* ln_w  = (const float*)d_in[5];
    const float* ln_b  = (const float*)d_in[6];

    char* ws = (char*)d_ws;
    // [0,8M) Qb | [8,16M) Kb | [16,24M) Vt | [24,32M) ctx | [32,32.25M) ml(l, fp32) |
    // x_bf [33,41M), wq_bf [41,47M) live only until gemm_qkv;
    // wo_bf [16,18M) after flash (Vt dead); ao fp32 [0,16M) after aw (Qb/Kb dead).
    bf16*   Qb    = (bf16*)(ws);
    bf16*   Kb    = (bf16*)(ws + (8ull  << 20));
    bf16*   Vt    = (bf16*)(ws + (16ull << 20));
    bf16*   ctx   = (bf16*)(ws + (24ull << 20));
    float*  ml    = (float*)(ws + (32ull << 20));
    bf16*   x_bf  = (bf16*)(ws + (33ull << 20));
    bf16*   wq_bf = (bf16*)(ws + (41ull << 20));
    bf16*   wo_bf = (bf16*)(ws + (16ull << 20));
    float*  ao    = (float*)(ws);

    float* y_out  = (float*)d_out;
    float* aw_out = y_out + 4ull * 1024 * 1024;

    cvt3_kernel<<<7168, 256, 0, stream>>>(x, x_bf, 1048576, w_qkv, wq_bf, 786432);
    gemm_qkv_kernel<<<dim3(24, 32), 256, 0, stream>>>(x_bf, wq_bf, b_qkv, Qb, Kb, Vt);
    flash_kernel<<<512, 512, 0, stream>>>(Qb, Kb, Vt, ctx, ml);
    aw_kernel<<<1024, 512, 0, stream>>>(Qb, Kb, ml, aw_out, w_out, wo_bf);
    gemm_out_kernel<<<dim3(8, 64), 256, 0, stream>>>(ctx, wo_bf, b_out, ao);
    ln_kernel<<<4096, 256, 0, stream>>>(x, ao, ln_w, ln_b, y_out);
}

// Round 7
// 192.800 us; speedup vs baseline: 1.1483x; 1.0437x over previous
//
#include <hip/hip_runtime.h>
#include <cstdint>

typedef __bf16 bf16;
typedef __bf16 bf16x8 __attribute__((ext_vector_type(8)));
typedef __bf16 bf16x4 __attribute__((ext_vector_type(4)));
typedef float  f32x4  __attribute__((ext_vector_type(4)));

#define MFMA_BF16(a, b, c) __builtin_amdgcn_mfma_f32_16x16x32_bf16(a, b, c, 0, 0, 0)

#define WAITCNT_VM(n) asm volatile("s_waitcnt vmcnt(" #n ")" ::: "memory")
#define CFENCE()      asm volatile("" ::: "memory")

// async global->LDS, 16B/lane; LDS dest affine in lane (base + lane*16).
__device__ __forceinline__ void async_load16(const void* g, void* l) {
    __builtin_amdgcn_global_load_lds(
        (__attribute__((address_space(1))) uint32_t*)(uintptr_t)g,
        (__attribute__((address_space(3))) uint32_t*)(uint32_t)(uintptr_t)l,
        16, 0, 0);
}

// ---------------- fused fp32 -> bf16 convert (x + w_qkv in one launch) ----------------
__global__ void cvt3_kernel(const float* __restrict__ s0, bf16* __restrict__ d0, int n0,
                            const float* __restrict__ s1, bf16* __restrict__ d1, int n1) {
    int i = blockIdx.x * blockDim.x + threadIdx.x;
    const float* s; bf16* d; int j = i;
    if (j < n0) { s = s0; d = d0; }
    else { j -= n0; if (j >= n1) return; s = s1; d = d1; }
    float4 v = ((const float4*)s)[j];
    bf16x4 o;
    o[0] = (bf16)v.x; o[1] = (bf16)v.y; o[2] = (bf16)v.z; o[3] = (bf16)v.w;
    ((bf16x4*)d)[j] = o;
}

// ---------------- QKV GEMM: 3-deep counted-vmcnt pipeline + T2 swizzle + T1 XCD remap ----------------
// Coalesced epilogue via LDS restage (padded stride 136): 8x contiguous 16B stores/thread.
__global__ __launch_bounds__(256) void gemm_qkv_kernel(
    const bf16* __restrict__ A, const bf16* __restrict__ W,
    const float* __restrict__ bias,
    bf16* __restrict__ Qb, bf16* __restrict__ Kb, bf16* __restrict__ Vt)
{
    const int Kd = 1024;
    __shared__ __attribute__((aligned(16))) bf16 smem[6 * 128 * 32];   // 48KB: sA[3] | sB[3]
    bf16* const sA0 = smem;
    bf16* const sB0 = smem + 3 * 4096;
    int tid = threadIdx.x, lane = tid & 63, wid = tid >> 6;
    int flat = blockIdx.y * 24 + blockIdx.x;          // 0..767
    int orig = (flat & 7) * 96 + (flat >> 3);         // XCD-contiguous (768 % 8 == 0)
    int m0 = (orig / 24) * 128, n0 = (orig % 24) * 128;
    int srow = wid * 32 + (lane >> 2);
    int pchunk = lane & 3;                       // physical chunk (LDS dest, linear)
    int jchunk = pchunk ^ ((lane >> 3) & 3);     // logical chunk (source); key=(srow>>1)&3
    const bf16* Ag = A + (size_t)(m0 + srow) * Kd + jchunk * 8;
    const bf16* Wg = W + (size_t)(n0 + srow) * Kd + jchunk * 8;
    int soff = srow * 32 + pchunk * 8;
    int wm = (wid & 1) * 64, wn = (wid >> 1) * 64;
    int lcol = lane & 15, quad = lane >> 4;
    int ckey = (lcol >> 1) & 3;                  // read-side swizzle key
    f32x4 acc[4][4] = {};
#define STG_Q(buf, k0_) do { \
        async_load16(Ag + (k0_), sA0 + (buf) * 4096 + soff); \
        async_load16(Ag + (k0_) + 16 * Kd, sA0 + (buf) * 4096 + soff + 512); \
        async_load16(Wg + (k0_), sB0 + (buf) * 4096 + soff); \
        async_load16(Wg + (k0_) + 16 * Kd, sB0 + (buf) * 4096 + soff + 512); \
    } while (0)
    STG_Q(0, 0);
    STG_Q(1, 32);
    STG_Q(2, 64);
    int cur = 0;
    for (int it = 0; it < 32; ++it) {
        if (it < 30)      { WAITCNT_VM(8); }
        else if (it == 30){ WAITCNT_VM(4); }
        else              { WAITCNT_VM(0); }
        __builtin_amdgcn_s_barrier();
        CFENCE();
        const bf16* cA = sA0 + cur * 4096;
        const bf16* cB = sB0 + cur * 4096;
        bf16x8 af[4], bfr[4];
#pragma unroll
        for (int i = 0; i < 4; i++)
            af[i] = *(const bf16x8*)&cA[(wm + i * 16 + lcol) * 32 + (quad ^ ckey) * 8];
#pragma unroll
        for (int i = 0; i < 4; i++)
            bfr[i] = *(const bf16x8*)&cB[(wn + i * 16 + lcol) * 32 + (quad ^ ckey) * 8];
#pragma unroll
        for (int i = 0; i < 4; i++)
#pragma unroll
            for (int j = 0; j < 4; j++)
                acc[i][j] = MFMA_BF16(af[i], bfr[j], acc[i][j]);
        CFENCE();
        __builtin_amdgcn_s_barrier();
        if (it + 3 < 32) STG_Q(cur, (it + 3) * 32);
        cur = (cur == 2) ? 0 : cur + 1;
    }
#undef STG_Q
    // ---- coalesced epilogue (LDS restage) ----
    const int LP = 136;                    // padded bf16 row stride (272B)
    bf16* sE = smem;                       // 128*136*2B = 34KB <= 48KB
    int part = n0 >> 10;                   // whole block is one of Q/K/V
    int h0 = (n0 & 1023) >> 6;
    int b = m0 >> 10, s0 = m0 & 1023;
    if (part == 2) {
#pragma unroll
        for (int j = 0; j < 4; j++) {
            float bv = bias[n0 + wn + j * 16 + lcol];
#pragma unroll
            for (int i = 0; i < 4; i++)
#pragma unroll
                for (int r = 0; r < 4; r++)
                    sE[(wn + j * 16 + lcol) * LP + (wm + i * 16 + quad * 4 + r)] = (bf16)(acc[i][j][r] + bv);
        }
        __syncthreads();
#pragma unroll
        for (int p = 0; p < 8; p++) {
            int c = p * 256 + tid;
            int nl = c >> 4, mc = (c & 15) * 8;
            int dd = nl & 63, h = h0 + (nl >> 6);
            *(bf16x8*)&Vt[(size_t)((b * 16 + h) * 64 + dd) * 1024 + s0 + mc] = *(const bf16x8*)&sE[nl * LP + mc];
        }
    } else {
        float scv = (part == 0) ? 0.125f : 1.0f;
        bf16* dst = (part == 0) ? Qb : Kb;
#pragma unroll
        for (int j = 0; j < 4; j++) {
            float bv = bias[n0 + wn + j * 16 + lcol];
#pragma unroll
            for (int i = 0; i < 4; i++)
#pragma unroll
                for (int r = 0; r < 4; r++)
                    sE[(wm + i * 16 + quad * 4 + r) * LP + (wn + j * 16 + lcol)] = (bf16)((acc[i][j][r] + bv) * scv);
        }
        __syncthreads();
#pragma unroll
        for (int p = 0; p < 8; p++) {
            int c = p * 256 + tid;
            int half = c >> 10, idx = c & 1023;
            int m = idx >> 3, nc = (idx & 7) * 8;
            *(bf16x8*)&dst[(size_t)((b * 16 + h0 + half) * 1024 + s0 + m) * 64 + nc] =
                *(const bf16x8*)&sE[m * LP + half * 64 + nc];
        }
    }
}

// ---------------- flash attention (+ piggybacked w_out cvt): 8-wave blocks ----------------
// Blocks 0..511: flash. Blocks 512..1023: w_out fp32->bf16 into ws+33M (x_bf slot, dead
// after qkv — no collision with live Vt). The cvt only needs to precede the merged
// aw/gemm_out kernel.
__global__ __launch_bounds__(512) void flash_kernel(
    const bf16* __restrict__ Qb, const bf16* __restrict__ Kb, const bf16* __restrict__ Vt,
    bf16* __restrict__ ctx, float* __restrict__ ml,
    const float* __restrict__ wof, bf16* __restrict__ wob)
{
    __shared__ bf16 sK[2][64 * 64];     // [buf][key][d], chunk-swizzled
    __shared__ bf16 sV[2][64 * 64];     // [buf][d][key], chunk-swizzled
    __shared__ bf16 pt[8][16 * 64];     // per-wave 16q x 64k transpose tile, XOR-swizzled
    int tid = threadIdx.x, lane = tid & 63, wid = tid >> 6;
    int bx = blockIdx.x;
    if (bx >= 512) {
        int i = (bx - 512) * 512 + tid;          // [0, 262144)
        float4 v = ((const float4*)wof)[i];
        bf16x4 o;
        o[0] = (bf16)v.x; o[1] = (bf16)v.y; o[2] = (bf16)v.z; o[3] = (bf16)v.w;
        ((bf16x4*)wob)[i] = o;
        return;
    }
    int orig = (bx & 7) * 64 + (bx >> 3);   // XCD-contiguous remap (bijective over 512)
    int qt = orig & 7;
    int h = (orig >> 3) & 15;
    int b = orig >> 7;
    int lcol = lane & 15, quad = lane >> 4;
    size_t base = (size_t)(b * 16 + h) * 65536;

    int q0 = qt * 128 + wid * 16;
    const bf16* qp = Qb + base + (size_t)(q0 + lcol) * 64 + quad * 8;
    bf16x8 a0 = *(const bf16x8*)qp;
    bf16x8 a1 = *(const bf16x8*)(qp + 32);

    char* wpt = (char*)&pt[wid][0];
    int sr = tid >> 3;                   // staged row 0..63
    int pp = tid & 7;                    // physical chunk
    int jj = pp ^ (sr & 7);              // logical chunk (swizzle key = row & 7)
    int sw = lcol & 7;                   // read-side swizzle key

#define STAGE_KV(buf, kt_) do { \
        async_load16(Kb + base + (size_t)((kt_) * 64 + sr) * 64 + jj * 8, &sK[buf][sr * 64 + pp * 8]); \
        async_load16(Vt + base + (size_t)sr * 1024 + (kt_) * 64 + jj * 8, &sV[buf][sr * 64 + pp * 8]); \
    } while (0)

    float l_[4] = {0.f, 0.f, 0.f, 0.f};
    f32x4 o[4] = {};

    STAGE_KV(0, 0);
    int cur = 0;
    for (int kt = 0; kt < 16; kt++) {
        __syncthreads();
        if (kt < 15) STAGE_KV(cur ^ 1, kt + 1);
        const bf16* sKc = &sK[cur][0];
        const bf16* sVc = &sV[cur][0];
#pragma unroll
        for (int nt = 0; nt < 4; nt++) {
            int ck = quad ^ sw;
            bf16x8 bk0 = *(const bf16x8*)&sKc[(nt * 16 + lcol) * 64 + ck * 8];
            bf16x8 bk1 = *(const bf16x8*)&sKc[(nt * 16 + lcol) * 64 + (ck ^ 4) * 8];
            f32x4 s = {};
            s = MFMA_BF16(a0, bk0, s);
            s = MFMA_BF16(a1, bk1, s);
#pragma unroll
            for (int rr = 0; rr < 4; rr++) {
                float p = __expf(s[rr]);
                l_[rr] += p;
                int row = quad * 4 + rr;
                *(bf16*)(wpt + row * 128 + ((nt * 32 + lcol * 2) ^ ((row & 7) << 4))) = (bf16)p;
            }
        }
#pragma unroll
        for (int kf = 0; kf < 2; kf++) {
            bf16x8 pa = *(const bf16x8*)(wpt + lcol * 128 + (((kf * 4 + quad) ^ sw) << 4));
#pragma unroll
            for (int dt = 0; dt < 4; dt++) {
                bf16x8 vb = *(const bf16x8*)&sVc[(dt * 16 + lcol) * 64 + ((kf * 4 + quad) ^ sw) * 8];
                o[dt] = MFMA_BF16(pa, vb, o[dt]);
            }
        }
        cur ^= 1;
    }
#undef STAGE_KV
#pragma unroll
    for (int mk = 1; mk < 16; mk <<= 1)
#pragma unroll
        for (int rr = 0; rr < 4; rr++) l_[rr] += __shfl_xor(l_[rr], mk, 64);
    // stage o -> pt (wave-private, swizzled), then coalesced 16B stores
#pragma unroll
    for (int rr = 0; rr < 4; rr++) {
        float inv = 1.f / l_[rr];
        int row = quad * 4 + rr;
#pragma unroll
        for (int dt = 0; dt < 4; dt++)
            *(bf16*)(wpt + row * 128 + ((dt * 32 + lcol * 2) ^ ((row & 7) << 4))) = (bf16)(o[dt][rr] * inv);
        if (lcol == 0)
            ml[(size_t)(b * 16 + h) * 1024 + q0 + row] = l_[rr];
    }
    int r8a = lane >> 3, ca = lane & 7;
#pragma unroll
    for (int half = 0; half < 2; half++) {
        int r8 = r8a + half * 8;
        bf16x8 v = *(const bf16x8*)(wpt + r8 * 128 + ((ca * 16) ^ ((r8 & 7) << 4)));
        *(bf16x8*)&ctx[(size_t)(b * 1024 + q0 + r8) * 1024 + h * 64 + ca * 8] = v;
    }
}

// ---------------- MERGED aw + out-proj GEMM (independent ops, one launch = overlap) ----------------
// Blocks 0..511: aw (8-wave, reg-pipelined Q/ml). Blocks 512..767: out-proj 128x128-tile
// GEMM (8-wave, 3-deep counted-vmcnt), writing ao into y_out (fp32 scratch; ln runs
// in-place after). 768 blocks x 48KB LDS = 3/CU, fully co-resident -> gemm hides under aw.
__global__ __launch_bounds__(512) void awo_kernel(
    const bf16* __restrict__ Qb, const bf16* __restrict__ Kb,
    const float* __restrict__ ml, float* __restrict__ aw,
    const bf16* __restrict__ ctx, const bf16* __restrict__ wob,
    const float* __restrict__ bias, float* __restrict__ yao)
{
    __shared__ __attribute__((aligned(16))) bf16 smem[6 * 128 * 32];   // 48KB union
    int tid = threadIdx.x, lane = tid & 63, wid = tid >> 6;
    int bx = blockIdx.x;
    int lcol = lane & 15, quad = lane >> 4;

    if (bx >= 512) {
        // ---- out-proj GEMM: 128x128 tile, 512 threads, 3-deep counted vmcnt ----
        const int Kd = 1024;
        bf16* const sA0 = smem;
        bf16* const sB0 = smem + 3 * 4096;
        int obx = bx - 512;                       // 0..255
        int m0 = (obx >> 3) * 128, n0 = (obx & 7) * 128;
        int srow = tid >> 2;                      // 0..127 (one 128x32 tile per stage)
        int pchunk = tid & 3;
        int jchunk = pchunk ^ ((tid >> 3) & 3);   // key=(srow>>1)&3
        const bf16* Ag = ctx + (size_t)(m0 + srow) * Kd + jchunk * 8;
        const bf16* Wg = wob + (size_t)(n0 + srow) * Kd + jchunk * 8;
        int soff = srow * 32 + pchunk * 8;
        int wm = (wid & 3) * 32, wn = (wid >> 2) * 64;
        int ckey = (lcol >> 1) & 3;
        f32x4 acc[2][4] = {};
#define STG_O(buf, k0_) do { \
        async_load16(Ag + (k0_), sA0 + (buf) * 4096 + soff); \
        async_load16(Wg + (k0_), sB0 + (buf) * 4096 + soff); \
    } while (0)
        STG_O(0, 0);
        STG_O(1, 32);
        STG_O(2, 64);
        int cur = 0;
        for (int it = 0; it < 32; ++it) {
            if (it < 30)      { WAITCNT_VM(4); }
            else if (it == 30){ WAITCNT_VM(2); }
            else              { WAITCNT_VM(0); }
            __builtin_amdgcn_s_barrier();
            CFENCE();
            const bf16* cA = sA0 + cur * 4096;
            const bf16* cB = sB0 + cur * 4096;
            bf16x8 af[2], bfr[4];
#pragma unroll
            for (int i = 0; i < 2; i++)
                af[i] = *(const bf16x8*)&cA[(wm + i * 16 + lcol) * 32 + (quad ^ ckey) * 8];
#pragma unroll
            for (int j = 0; j < 4; j++)
                bfr[j] = *(const bf16x8*)&cB[(wn + j * 16 + lcol) * 32 + (quad ^ ckey) * 8];
#pragma unroll
            for (int i = 0; i < 2; i++)
#pragma unroll
                for (int j = 0; j < 4; j++)
                    acc[i][j] = MFMA_BF16(af[i], bfr[j], acc[i][j]);
            CFENCE();
            __builtin_amdgcn_s_barrier();
            if (it + 3 < 32) STG_O(cur, (it + 3) * 32);
            cur = (cur == 2) ? 0 : cur + 1;
        }
#undef STG_O
#pragma unroll
        for (int j = 0; j < 4; j++) {
            int n = n0 + wn + j * 16 + lcol;
            float bv = bias[n];
#pragma unroll
            for (int i = 0; i < 2; i++) {
                int m = m0 + wm + i * 16 + quad * 4;
#pragma unroll
                for (int r = 0; r < 4; r++) yao[(size_t)(m + r) * 1024 + n] = acc[i][j][r] + bv;
            }
        }
        return;
    }

    // ---- aw: 8-wave, dbuf K staging, reg-pipelined Q/ml ----
    bf16* const sK0 = smem;                       // 2 x 4096 elements
    int orig = (bx & 7) * 64 + (bx >> 3);         // bijective over 512
    int kt = orig & 15;
    int qt = (orig >> 4) & 7;
    int b = orig >> 7;
    int q0 = qt * 128 + wid * 16;
    int kbase = kt * 64;
    int sw = lcol & 7;
    int sr = tid >> 3, pp = tid & 7, jj = pp ^ (sr & 7);   // 1 chunk per thread (8KB)

#define STAGE_K(buf, hh) \
        async_load16(Kb + (size_t)(b * 16 + (hh)) * 65536 + (size_t)(kbase + sr) * 64 + jj * 8, \
                     sK0 + (buf) * 4096 + sr * 64 + pp * 8)

    float acc[16];
#pragma unroll
    for (int i = 0; i < 16; i++) acc[i] = 0.f;

    bf16x8 a0c, a1c, a0n, a1n;
    float4 mvC, mvN;
    {
        const bf16* qp = Qb + (size_t)(b * 16) * 65536 + (size_t)(q0 + lcol) * 64 + quad * 8;
        a0c = *(const bf16x8*)qp;
        a1c = *(const bf16x8*)(qp + 32);
        mvC = *(const float4*)(ml + (size_t)(b * 16) * 1024 + q0 + quad * 4);
    }
    STAGE_K(0, 0);
    int cur = 0;
    for (int h = 0; h < 16; h++) {
        __syncthreads();
        if (h < 15) {
            STAGE_K(cur ^ 1, h + 1);
            const bf16* qp = Qb + (size_t)(b * 16 + h + 1) * 65536 + (size_t)(q0 + lcol) * 64 + quad * 8;
            a0n = *(const bf16x8*)qp;
            a1n = *(const bf16x8*)(qp + 32);
            mvN = *(const float4*)(ml + (size_t)(b * 16 + h + 1) * 1024 + q0 + quad * 4);
        }
        float scale[4] = {0.0625f / mvC.x, 0.0625f / mvC.y, 0.0625f / mvC.z, 0.0625f / mvC.w};
        const bf16* sKc = sK0 + cur * 4096;
#pragma unroll
        for (int nt = 0; nt < 4; nt++) {
            int ck = quad ^ sw;
            bf16x8 bk0 = *(const bf16x8*)&sKc[(nt * 16 + lcol) * 64 + ck * 8];
            bf16x8 bk1 = *(const bf16x8*)&sKc[(nt * 16 + lcol) * 64 + (ck ^ 4) * 8];
            f32x4 s = {};
            s = MFMA_BF16(a0c, bk0, s);
            s = MFMA_BF16(a1c, bk1, s);
#pragma unroll
            for (int rr = 0; rr < 4; rr++)
                acc[nt * 4 + rr] += __expf(s[rr]) * scale[rr];
        }
        if (h < 15) { a0c = a0n; a1c = a1n; mvC = mvN; }
        cur ^= 1;
    }
#undef STAGE_K
#pragma unroll
    for (int nt = 0; nt < 4; nt++)
#pragma unroll
        for (int rr = 0; rr < 4; rr++)
            aw[(size_t)(b * 1024 + q0 + quad * 4 + rr) * 1024 + kbase + nt * 16 + lcol] = acc[nt * 4 + rr];
}

// ---------------- residual + LayerNorm (in-place over yao = y_out) ----------------
__global__ __launch_bounds__(256) void ln_kernel(
    const float* __restrict__ x, const float* __restrict__ ao,
    const float* __restrict__ w, const float* __restrict__ bsh,
    float* __restrict__ y)
{
    int row = blockIdx.x, tid = threadIdx.x;
    float4 xv = ((const float4*)(x + (size_t)row * 1024))[tid];
    float4 av = ((const float4*)(ao + (size_t)row * 1024))[tid];
    float4 v = {xv.x + av.x, xv.y + av.y, xv.z + av.z, xv.w + av.w};
    float s = v.x + v.y + v.z + v.w;
    float ss = v.x * v.x + v.y * v.y + v.z * v.z + v.w * v.w;
#pragma unroll
    for (int off = 32; off; off >>= 1) { s += __shfl_down(s, off); ss += __shfl_down(ss, off); }
    __shared__ float rs[4], rss[4];
    int lane = tid & 63, wid = tid >> 6;
    if (lane == 0) { rs[wid] = s; rss[wid] = ss; }
    __syncthreads();
    s = rs[0] + rs[1] + rs[2] + rs[3];
    ss = rss[0] + rss[1] + rss[2] + rss[3];
    float mean = s * (1.f / 1024.f);
    float var = ss * (1.f / 1024.f) - mean * mean;
    float inv = rsqrtf(var + 1e-5f);
    float4 wv = ((const float4*)w)[tid];
    float4 bv = ((const float4*)bsh)[tid];
    float4 o;
    o.x = (v.x - mean) * inv * wv.x + bv.x;
    o.y = (v.y - mean) * inv * wv.y + bv.y;
    o.z = (v.z - mean) * inv * wv.z + bv.z;
    o.w = (v.w - mean) * inv * wv.w + bv.w;
    ((float4*)y)[row * 256 + tid] = o;
}

extern "C" void kernel_launch(void* const* d_in, const int* in_sizes, int n_in,
                              void* d_out, int out_size, void* d_ws, size_t ws_size,
                              hipStream_t stream) {
    const float* x     = (const float*)d_in[0];
    const float* w_qkv = (const float*)d_in[1];
    const float* b_qkv = (const float*)d_in[2];
    const float* w_out = (const float*)d_in[3];
    const float* b_out = (const float*)d_in[4];
    const float* ln_w  = (const float*)d_in[5];
    const float* ln_b  = (const float*)d_in[6];

    char* ws = (char*)d_ws;
    // [0,8M) Qb | [8,16M) Kb | [16,24M) Vt | [24,32M) ctx | [32,32.25M) ml |
    // x_bf [33,41M), wq_bf [41,47M) live only until gemm_qkv;
    // wo_bf [33,35M) after qkv (x_bf dead; written by flash-launch cvt riders);
    // ao lives in y_out (d_out scratch; ln runs in-place).
    bf16*   Qb    = (bf16*)(ws);
    bf16*   Kb    = (bf16*)(ws + (8ull  << 20));
    bf16*   Vt    = (bf16*)(ws + (16ull << 20));
    bf16*   ctx   = (bf16*)(ws + (24ull << 20));
    float*  ml    = (float*)(ws + (32ull << 20));
    bf16*   x_bf  = (bf16*)(ws + (33ull << 20));
    bf16*   wq_bf = (bf16*)(ws + (41ull << 20));
    bf16*   wo_bf = (bf16*)(ws + (33ull << 20));

    float* y_out  = (float*)d_out;
    float* aw_out = y_out + 4ull * 1024 * 1024;
    float* ao     = y_out;                      // scratch; ln in-place

    cvt3_kernel<<<7168, 256, 0, stream>>>(x, x_bf, 1048576, w_qkv, wq_bf, 786432);
    gemm_qkv_kernel<<<dim3(24, 32), 256, 0, stream>>>(x_bf, wq_bf, b_qkv, Qb, Kb, Vt);
    flash_kernel<<<1024, 512, 0, stream>>>(Qb, Kb, Vt, ctx, ml, w_out, wo_bf);
    awo_kernel<<<768, 512, 0, stream>>>(Qb, Kb, ml, aw_out, ctx, wo_bf, b_out, ao);
    ln_kernel<<<4096, 256, 0, stream>>>(x, ao, ln_w, ln_b, y_out);
}